// Round 7
// baseline (466.012 us; speedup 1.0000x reference)
//
#include <hip/hip_runtime.h>

// ---------------------------------------------------------------------------
// DistanceLoss pipeline on MI355X (gfx950)  — R21
//
// R4: tuple-gather factored out of embed GEMM. R9: split-K=2 GEMMs.
// R10: build_e2 sample-tiled. R15: 8-wave gemm. R16: pair schedule.
// R17: distance-3 counted vmcnt regressed. R18: XCD swizzle hurt locality.
// R19: cooperative launch failed under harness. R20: 3-stage ring,
//      3 blocks/CU, distance-2 prefetch, counted vmcnt(2) — 213.9us best.
// R21a: gemm2 LAST-BLOCK FINALIZE: per-tile device atomic counter; second
//       finisher (acc in regs) reads the other split-K partial (L2-hot),
//       computes D = sqrt(sq_r+sq_c-2p) and writes D directly. Kills
//       dist_stats' 41.5MB partial re-read + D write pass. Bit-identical D
//       (two-operand float add commutes). Fences per Guideline 16.
// R21b: dist_stats -> stats_only (3375 query rows, read-only).
// R21c: tail_fused 512 threads (phase B over 8 waves).
//
//  1. prep: W fp32->split bf16; X bf16; zero record/sq/cnt
//  2. gemm_ring grid(8,32,2):  Yz = X @ Wsplit^T (half-K partials, fp32)
//  3. build_e2: E rows (bf16) from Y0+Y1, sample-tiled; sq via atomics
//  4. gemm_ring grid(36,9,2):  partials + last-block D finalize
//  5. stats_only(3375): per-(c,i) ave/pos/rmax from D rows
//  6. record_part(675)
//  7. tail_fused(75x512): thr/mask/msum + masked row sums + logits
// ---------------------------------------------------------------------------

typedef __bf16 bf16x8 __attribute__((ext_vector_type(8)));
typedef float f32x4 __attribute__((ext_vector_type(4)));

#define NQT   3375      // 75*45 query-tuple rows
#define MROWS 4500      // 3375 query rows + 1125 support rows
#define MPAD  4608      // 36 * 128
#define LDD   1152      // padded 1125 -> 9*128
#define BK    32        // K-tile; LDS stride = 32 (UNPADDED: required by global_load_lds)

__constant__ int P0[45] = {0,0,0,0,0,0,0,0,0,
                           1,1,1,1,1,1,1,1,
                           2,2,2,2,2,2,2,
                           3,3,3,3,3,3,
                           4,4,4,4,4,
                           5,5,5,5,
                           6,6,6,
                           7,7,
                           8};
__constant__ int P1[45] = {1,2,3,4,5,6,7,8,9,
                           2,3,4,5,6,7,8,9,
                           3,4,5,6,7,8,9,
                           4,5,6,7,8,9,
                           5,6,7,8,9,
                           6,7,8,9,
                           7,8,9,
                           8,9,
                           9};

__device__ inline unsigned short f2b(float x) {
  __bf16 b = (__bf16)x;               // RNE
  return __builtin_bit_cast(unsigned short, b);
}
__device__ inline float b2f(unsigned int u16) {
  return __uint_as_float(u16 << 16);
}

// async global->LDS, 16B per lane; lds dest must be wave-uniform base + lane*16
__device__ __forceinline__ void gl_lds16(const unsigned short* g, unsigned short* l) {
  __builtin_amdgcn_global_load_lds(
      (__attribute__((address_space(1))) void*)(g),
      (__attribute__((address_space(3))) void*)(l),
      16, 0, 0);
}

// ---- 1: prep: conv W (split) + conv X + zero record/sq/cnt -----------------
__global__ void prep(const float* __restrict__ W, const float* __restrict__ Q,
                     const float* __restrict__ Sp,
                     unsigned short* __restrict__ Ws, unsigned short* __restrict__ X,
                     float* __restrict__ record, float* __restrict__ sq,
                     int* __restrict__ cnt) {
  int b = blockIdx.x, tid = threadIdx.x;
  if (b < 8192) {                                    // W -> split bf16
    int i = b * 256 + tid;
    int i4 = i << 2;
    int o  = i4 >> 12;
    int k  = i4 & 4095;
    int hf = k >> 11;
    int kk = k & 2047;
    float4 v = reinterpret_cast<const float4*>(W)[i];
    ushort4 u;
    u.x = f2b(v.x); u.y = f2b(v.y); u.z = f2b(v.z); u.w = f2b(v.w);
    *reinterpret_cast<ushort4*>(Ws + (size_t)(o + hf * 2048) * 2048 + kk) = u;
  } else if (b < 10240) {                            // X = bf16(Q || S), pad 0
    int i = (b - 8192) * 256 + tid;
    ushort4 u = {0, 0, 0, 0};
    if (i < 384000) {                                // 750*2048/4
      float4 v = reinterpret_cast<const float4*>(Q)[i];
      u.x = f2b(v.x); u.y = f2b(v.y); u.z = f2b(v.z); u.w = f2b(v.w);
    } else if (i < 512000) {                         // + 250*2048/4
      float4 v = reinterpret_cast<const float4*>(Sp)[i - 384000];
      u.x = f2b(v.x); u.y = f2b(v.y); u.z = f2b(v.z); u.w = f2b(v.w);
    }
    reinterpret_cast<ushort4*>(X)[i] = u;
  } else {                                           // zero record + sq + cnt
    int i = (b - 10240) * 256 + tid;
    if (i < 4500) record[i] = 0.f;
    else if (i < 9108) sq[i - 4500] = 0.f;
    else if (i < 9432) cnt[i - 9108] = 0;
  }
}

// ---- 2/4: bf16 MFMA GEMM, C = A @ B^T, 128x128 tile, BK=32, split-K --------
// 512 threads / 8 waves (2x4 wave grid, 64x32 output per wave).
// 3-stage ring (48 KB -> 3 blocks/CU), distance-2 prefetch, counted vmcnt(2).
// R21: if Dfin != nullptr, last-block-per-tile finalize: second finisher
// reads the other K-half partial and writes D = sqrt(sq_r + sq_c - 2p).
// NOTE: Pout0/Pout1/Dfin are NOT restrict — Dfin aliases Pout0 by design.
__global__ __launch_bounds__(512)
void gemm_ring(const unsigned short* __restrict__ A, const unsigned short* __restrict__ B,
               int lda, int ldb, int Ksplit,
               float* Pout0, float* Pout1, int ldd,
               const float* __restrict__ sqv, float* Dfin, int* cnt) {
  __shared__ unsigned short As[3][128 * BK];   // 3 x 8 KB
  __shared__ unsigned short Bs[3][128 * BK];
  const int tid  = threadIdx.x;
  const int wave = tid >> 6, lane = tid & 63;
  const int quad = lane >> 4, l16 = lane & 15;
  const int wm = (wave >> 2) * 64, wn = (wave & 3) * 32;
  const int m0 = blockIdx.x * 128, n0 = blockIdx.y * 128;
  const int kbase = blockIdx.z * Ksplit;

  f32x4 acc[4][2];
#pragma unroll
  for (int i = 0; i < 4; ++i)
#pragma unroll
    for (int j = 0; j < 2; ++j) {
      f32x4 z = {0.f, 0.f, 0.f, 0.f};
      acc[i][j] = z;
    }

  const int r0  = tid >> 2;                          // 0..127
  const int qsw = (tid & 3) ^ ((tid >> 3) & 3);      // swizzled global chunk
  const int kp0 = qsw * 8;
  const int rsw = (quad ^ ((l16 >> 1) & 3)) * 8;     // conflict-free read slot
  const unsigned short* pa = A + (size_t)(m0 + r0) * lda + kbase + kp0;
  const unsigned short* pb = B + (size_t)(n0 + r0) * ldb + kbase + kp0;
  const int NKi = Ksplit / BK;                       // 32

// one full 128-row stage per array: 512 threads x 16B = 8 KB
#define ISSUE(kk, st) do {                                 \
    gl_lds16(pa + (size_t)(kk) * BK, &As[st][wave * 512]); \
    gl_lds16(pb + (size_t)(kk) * BK, &Bs[st][wave * 512]); \
  } while (0)

  ISSUE(0, 0);
  ISSUE(1, 1);
  asm volatile("s_waitcnt vmcnt(2)" ::: "memory");   // tile 0 resident; 1 in flight
  __builtin_amdgcn_s_barrier();

  int sc = 0;
  for (int k = 0; k < NKi; ++k) {
    int sn = sc + 2; if (sn >= 3) sn -= 3;
    if (k + 2 < NKi) ISSUE(k + 2, sn);               // distance-2 prefetch
    bf16x8 af[4], bfr[2];
#pragma unroll
    for (int t = 0; t < 4; ++t)
      af[t] = *reinterpret_cast<const bf16x8*>(&As[sc][(wm + t * 16 + l16) * BK + rsw]);
#pragma unroll
    for (int t = 0; t < 2; ++t)
      bfr[t] = *reinterpret_cast<const bf16x8*>(&Bs[sc][(wn + t * 16 + l16) * BK + rsw]);
#pragma unroll
    for (int i = 0; i < 4; ++i)
#pragma unroll
      for (int j = 0; j < 2; ++j)
        acc[i][j] = __builtin_amdgcn_mfma_f32_16x16x32_bf16(af[i], bfr[j], acc[i][j], 0, 0, 0);
    if (k + 1 < NKi) {
      // guarantee tile k+1 resident; leave k+2 (if issued) in flight
      if (k + 2 < NKi) asm volatile("s_waitcnt vmcnt(2)" ::: "memory");
      else             asm volatile("s_waitcnt vmcnt(0)" ::: "memory");
      __builtin_amdgcn_s_barrier();
    }
    sc = sc + 1; if (sc >= 3) sc = 0;
  }
#undef ISSUE
  asm volatile("s_waitcnt vmcnt(0)" ::: "memory");   // drain before stores

  float* Pout = blockIdx.z ? Pout1 : Pout0;
  // epilogue: C/D layout col=lane&15, row=quad*4+reg
#pragma unroll
  for (int i = 0; i < 4; ++i)
#pragma unroll
    for (int j = 0; j < 2; ++j) {
      int col = n0 + wn + j * 16 + l16;
      int rbase = m0 + wm + i * 16 + quad * 4;
      f32x4 v = acc[i][j];
#pragma unroll
      for (int r = 0; r < 4; ++r)
        Pout[(size_t)(rbase + r) * ldd + col] = v[r];
    }

  if (Dfin == nullptr) return;
  // ---- last-block distance finalize (device-scope handshake) ----
  __threadfence();                                   // release own partial
  __shared__ int lastf;
  if (tid == 0)
    lastf = (atomicAdd(&cnt[blockIdx.y * gridDim.x + blockIdx.x], 1) == 1);
  __syncthreads();
  if (!lastf) return;
  __threadfence();                                   // acquire other partial
  const float* Po = blockIdx.z ? Pout0 : Pout1;      // other K-half
#pragma unroll
  for (int i = 0; i < 4; ++i) {
    int rbase = m0 + wm + i * 16 + quad * 4;
    float sr[4];
#pragma unroll
    for (int r = 0; r < 4; ++r) sr[r] = sqv[rbase + r];
#pragma unroll
    for (int j = 0; j < 2; ++j) {
      int col = n0 + wn + j * 16 + l16;
      float scq = sqv[NQT + col];
      f32x4 v = acc[i][j];
#pragma unroll
      for (int r = 0; r < 4; ++r) {
        float p = v[r] + Po[(size_t)(rbase + r) * ldd + col];
        Dfin[(size_t)(rbase + r) * ldd + col] =
            sqrtf(fmaxf(sr[r] + scq - 2.f * p, 0.f));
      }
    }
  }
}

// ---- 3: build_e2: sample-tiled E construction ------------------------------
__global__ __launch_bounds__(256)
void build_e2(const float* __restrict__ Y0, const float* __restrict__ Y1,
              const float* __restrict__ bias,
              unsigned short* __restrict__ E, float* __restrict__ sq) {
  int b = blockIdx.x, tid = threadIdx.x;
  if (b >= 400) {                       // zero pad rows
    const size_t base = (size_t)4500 * 2048 / 8;   // uint4 index
    const int total = 108 * 2048 / 8;              // 27648
    uint4 z = {0, 0, 0, 0};
    for (int i = (b - 400) * 256 + tid; i < total; i += 512)
      reinterpret_cast<uint4*>(E)[base + i] = z;
    return;
  }
  int n = b >> 2, q = b & 3;
  int c0 = q * 512;
  __shared__ float Lf[10][512];
  __shared__ float Rf[10][512];
  // stage: 10 frames x 512 cols x {left,right}, Y0+Y1 summed
  for (int e = tid; e < 1280; e += 256) {           // 1280 float4 slots per array
    int f  = e >> 7;                                // 128 float4 per frame
    int cc = (e & 127) << 2;
    const float* ya = Y0 + (size_t)(n * 10 + f) * 4096;
    const float* yb = Y1 + (size_t)(n * 10 + f) * 4096;
    float4 l0 = *reinterpret_cast<const float4*>(ya + c0 + cc);
    float4 l1 = *reinterpret_cast<const float4*>(yb + c0 + cc);
    float4 r0 = *reinterpret_cast<const float4*>(ya + 2048 + c0 + cc);
    float4 r1 = *reinterpret_cast<const float4*>(yb + 2048 + c0 + cc);
    float4 L = {l0.x + l1.x, l0.y + l1.y, l0.z + l1.z, l0.w + l1.w};
    float4 R = {r0.x + r1.x, r0.y + r1.y, r0.z + r1.z, r0.w + r1.w};
    *reinterpret_cast<float4*>(&Lf[f][cc]) = L;
    *reinterpret_cast<float4*>(&Rf[f][cc]) = R;
  }
  __syncthreads();
  int wv = tid >> 6, lane = tid & 63;
  int erow0 = (n < 75) ? n * 45 : NQT + (n - 75) * 45;
  for (int t = wv; t < 45; t += 4) {
    int f0 = P0[t], f1 = P1[t];
    int row = erow0 + t;
    float s = 0.f;
#pragma unroll
    for (int k = 0; k < 8; ++k) {
      int c = lane + 64 * k;                        // 0..511
      float x = Lf[f0][c] + Rf[f1][c] + bias[c0 + c];
      x = fmaxf(x, 0.f);
      unsigned short ob = f2b(x);
      E[(size_t)row * 2048 + c0 + c] = ob;
      float xr = b2f(ob);
      s += xr * xr;                                 // norm from rounded value
    }
#pragma unroll
    for (int sh = 32; sh > 0; sh >>= 1) s += __shfl_down(s, sh, 64);
    if (lane == 0) atomicAdd(&sq[row], s);
  }
}

// ---- 5: stats_only: per-class stats for query rows (D already final) -------
__global__ __launch_bounds__(320)
void stats_only(const float* __restrict__ D, float* __restrict__ ave,
                int* __restrict__ pos, float* __restrict__ rmax) {
  __shared__ float drow[LDD];
  __shared__ float sm[5][64];
  int row = blockIdx.x, tid = threadIdx.x;          // row 0..3374
  if (tid < 288) {                                  // 288 float4 = 1152 cols
    size_t ix = (size_t)row * LDD / 4 + tid;
    reinterpret_cast<float4*>(drow)[tid] = reinterpret_cast<const float4*>(D)[ix];
  }
  __syncthreads();
  int wv = tid >> 6, lane = tid & 63;               // wv = class 0..4
  const float* p = &drow[wv * 225];
  float best = -1e30f; int bi = 225;
  float gm = -1e30f;
  if (lane < 60) {
#pragma unroll
    for (int r = 0; r < 4; ++r) {
      int j = lane + 60 * r;
      if (j < 225) {
        float v = p[j];
        if (v > best) { best = v; bi = j; }          // first-occurrence (j asc)
        gm = fmaxf(gm, v);
      }
    }
  }
#pragma unroll
  for (int s = 32; s > 0; s >>= 1) {
    float vv = __shfl_down(best, s, 64);
    int   ii = __shfl_down(bi,   s, 64);
    if (vv > best || (vv == best && ii < bi)) { best = vv; bi = ii; }
  }
  sm[wv][lane] = gm;
  __builtin_amdgcn_wave_barrier();
  if (lane < 5) {
    float m = -1e30f;
#pragma unroll
    for (int a = 0; a < 12; ++a) m = fmaxf(m, sm[wv][lane + 5 * a]);
    sm[wv][lane] = m;
  }
  __builtin_amdgcn_wave_barrier();
  if (lane == 0) {
    float s5 = sm[wv][0] + sm[wv][1] + sm[wv][2] + sm[wv][3] + sm[wv][4];
    ave[wv * NQT + row]  = s5 * 0.2f;
    pos[wv * NQT + row]  = bi;
    rmax[wv * NQT + row] = best;
  }
}

// ---- 6a: record counts, 675 blocks (5 classes x 135 chunks of 25) ----------
__global__ void record_part(const float* __restrict__ D, const float* __restrict__ ave,
                            const int* __restrict__ pos, float* __restrict__ record) {
  int b = blockIdx.x;
  int c = b / 135, chunk = b - c * 135;
  int i0 = chunk * 25;
  int tid = threadIdx.x;
  __shared__ int   sp[25];
  __shared__ float sa[25];
  if (tid < 25) {
    sp[tid] = pos[c * NQT + i0 + tid];
    sa[tid] = ave[c * NQT + i0 + tid];
  }
  __syncthreads();
  float cnt[4] = {0.f, 0.f, 0.f, 0.f};
  int gcol[4];
#pragma unroll
  for (int j = 0; j < 4; ++j) {
    int col = tid + j * 256;
    gcol[j] = (col < 900) ? (col < c * 225 ? col : col + 225) : 0;
  }
  const bool act3 = (tid + 768) < 900;
  const float* Dsup = D + (size_t)(NQT + c * 225) * LDD;
  for (int ii = 0; ii < 25; ++ii) {
    const float* row = Dsup + (size_t)sp[ii] * LDD;
    float a = sa[ii];
    cnt[0] += (row[gcol[0]] > a) ? 1.f : 0.f;
    cnt[1] += (row[gcol[1]] > a) ? 1.f : 0.f;
    cnt[2] += (row[gcol[2]] > a) ? 1.f : 0.f;
    if (act3) cnt[3] += (row[gcol[3]] > a) ? 1.f : 0.f;
  }
#pragma unroll
  for (int j = 0; j < 4; ++j) {
    int col = tid + j * 256;
    if (col < 900) atomicAdd(&record[c * 900 + col], cnt[j]);
  }
}

// ---- 7: tail_fused: thr/mask/msum + masked row sums + logits ---------------
// 75 blocks x 512 threads (8 waves). Masks recomputed per-block from record
// (integer-valued floats -> sums exact -> identical thr/mask/msum).
__global__ __launch_bounds__(512)
void tail_fused(const float* __restrict__ D, const float* __restrict__ record,
                const float* __restrict__ rmax, float* __restrict__ out) {
  int q = blockIdx.x;                                // 0..74
  int tid = threadIdx.x;
  int wv = tid >> 6, lane = tid & 63;
  __shared__ float maskT[5 * LDD];                   // 23 KB
  __shared__ float msum_s[5];
  __shared__ float St[5][45];
  for (int i = tid; i < 5 * LDD; i += 512) maskT[i] = 0.f;
  if (tid < 5) msum_s[tid] = 0.f;
  __syncthreads();

  // Phase A: 20 segments (c,mi), one wave each, strided over 8 waves
  for (int seg = wv; seg < 20; seg += 8) {
    int c = seg >> 2, mi = seg & 3;
    const float* rec = record + c * 900 + mi * 225;
    float r0 = rec[lane];
    float r1 = rec[lane + 64];
    float r2 = rec[lane + 128];
    float r3 = (lane + 192 < 225) ? rec[lane + 192] : 0.f;
    float s  = r0 + r1 + r2 + r3;
    float nz = (r0 != 0.f ? 1.f : 0.f) + (r1 != 0.f ? 1.f : 0.f) +
               (r2 != 0.f ? 1.f : 0.f) + (r3 != 0.f ? 1.f : 0.f);
#pragma unroll
    for (int sh = 32; sh > 0; sh >>= 1) {
      s  += __shfl_down(s,  sh, 64);
      nz += __shfl_down(nz, sh, 64);
    }
    s  = __shfl(s,  0, 64);
    nz = __shfl(nz, 0, 64);
    float nzc = nz < 1.f ? 1.f : nz;
    float thr = s / nzc;
    float mcount = 0.f;
    float rv[4] = {r0, r1, r2, r3};
#pragma unroll
    for (int j = 0; j < 4; ++j) {
      int idx = lane + j * 64;
      if (idx < 225) {
        float m = (rv[j] < thr) ? 1.f : 0.f;
        int L = mi * 225 + idx;                      // local col 0..899
        int g = L + (L >= c * 225 ? 225 : 0);        // global support col
        maskT[c * LDD + g] = m;
        mcount += m;
      }
    }
#pragma unroll
    for (int sh = 32; sh > 0; sh >>= 1) mcount += __shfl_down(mcount, sh, 64);
    if (lane == 0) atomicAdd(&msum_s[c], mcount);
  }
  __syncthreads();

  // Phase B: rows t = wv, wv+8, ... (45 rows over 8 waves)
  for (int t = wv; t < 45; t += 8) {
    const float* row = D + (size_t)(q * 45 + t) * LDD;
    float a0 = 0.f, a1 = 0.f, a2 = 0.f, a3 = 0.f, a4 = 0.f;
#pragma unroll
    for (int k = 0; k < 18; ++k) {                   // 18*64 = 1152 cols
      int col = k * 64 + lane;
      float d = row[col];
      a0 += d * maskT[0 * LDD + col];
      a1 += d * maskT[1 * LDD + col];
      a2 += d * maskT[2 * LDD + col];
      a3 += d * maskT[3 * LDD + col];
      a4 += d * maskT[4 * LDD + col];
    }
#pragma unroll
    for (int sh = 32; sh > 0; sh >>= 1) {
      a0 += __shfl_down(a0, sh, 64);
      a1 += __shfl_down(a1, sh, 64);
      a2 += __shfl_down(a2, sh, 64);
      a3 += __shfl_down(a3, sh, 64);
      a4 += __shfl_down(a4, sh, 64);
    }
    if (lane == 0) {
      St[0][t] = a0; St[1][t] = a1; St[2][t] = a2; St[3][t] = a3; St[4][t] = a4;
    }
  }
  __syncthreads();

  // Phase C: per-class aggregate + logits
  if (tid < 5) {
    int c = tid;
    float dsum = 0.f, ssum = 0.f;
    for (int t = 0; t < 45; ++t) {
      dsum += rmax[c * NQT + q * 45 + t];
      ssum += St[c][t];
    }
    float dm = dsum / 45.f;
    float ms = msum_s[c]; if (ms < 1.f) ms = 1.f;
    float contrast = ssum / (ms * 180.f);            // /msum /45 /(WAY-1)
    out[q * 5 + c] = dm;
    out[375 + q * 5 + c] = dm / (contrast + dm);
  }
}

// ---------------------------------------------------------------------------
extern "C" void kernel_launch(void* const* d_in, const int* in_sizes, int n_in,
                              void* d_out, int out_size, void* d_ws, size_t ws_size,
                              hipStream_t stream) {
  const float* support = (const float*)d_in[0];
  // d_in[1] = support_labels (arange//SHOT) -- class gather is a reshape, unused
  const float* queries = (const float*)d_in[2];
  const float* W       = (const float*)d_in[3];
  const float* bias    = (const float*)d_in[4];
  float* out = (float*)d_out;

  // Aliased workspace layout (lifetimes):
  //  [0, 21.2 MB):  Xb (4.2) + Ws (16.8)   -- dead after gemm1 --> reused as Pd1
  //  [21.2, 38.0):  Y0 (fp32 1024x4096)    -- dead after build_e2
  //  [38.0, 59.2):  Dm region: Y1 (dead after build_e2) -> Pd0 -> D
  //  [59.2, 78.1):  Eb (bf16 4608x2048)
  //  then smalls
  char* ws = (char*)d_ws;
  size_t off = 0;
  unsigned short* Xb  = (unsigned short*)(ws + off);
  unsigned short* Wsp = (unsigned short*)(ws + off + 4194304);
  float*          Pd1 = (float*)(ws + off);          off += 21233664;
  float*          Y0  = (float*)(ws + off);          off += (size_t)1024 * 4096 * 4;
  float*          Dm  = (float*)(ws + off);          // Pd0 / final D
  float*          Y1  = (float*)(ws + off);          off += (size_t)MPAD * LDD * 4;
  unsigned short* Eb  = (unsigned short*)(ws + off); off += (size_t)MPAD * 2048 * 2;
  float* sq      = (float*)(ws + off); off += 4608 * 4 + 256;
  float* ave     = (float*)(ws + off); off += 5 * NQT * 4 + 256;
  int*   pos     = (int*)(ws + off);   off += 5 * NQT * 4 + 256;
  float* rmax    = (float*)(ws + off); off += 5 * NQT * 4 + 256;
  float* record  = (float*)(ws + off); off += 5 * 900 * 4 + 256;
  int*   cnt     = (int*)(ws + off);   off += 324 * 4 + 256;

  // zero tail: 4500 (record) + 4608 (sq) + 324 (cnt) = 9432 -> 37 blocks
  prep<<<10277, 256, 0, stream>>>(W, queries, support, Wsp, Xb, record, sq, cnt);

  dim3 g1(1024 / 128, 4096 / 128, 2);   // 8 x 32 x 2 = 512 blocks, K=1024 each
  gemm_ring<<<g1, 512, 0, stream>>>(Xb, Wsp, 2048, 2048, 1024, Y0, Y1, 4096,
                                    nullptr, nullptr, nullptr);

  build_e2<<<402, 256, 0, stream>>>(Y0, Y1, bias, Eb, sq);

  dim3 g2(MPAD / 128, LDD / 128, 2);    // 36 x 9 x 2 = 648 blocks, K=1024 each
  gemm_ring<<<g2, 512, 0, stream>>>(Eb, Eb + (size_t)NQT * 2048, 2048, 2048, 1024,
                                    Dm, Pd1, LDD, sq, Dm, cnt);

  stats_only<<<NQT, 320, 0, stream>>>(Dm, ave, pos, rmax);

  record_part<<<675, 256, 0, stream>>>(Dm, ave, pos, record);
  tail_fused<<<75, 512, 0, stream>>>(Dm, record, rmax, out);
}

// Round 8
// 226.398 us; speedup vs baseline: 2.0584x; 2.0584x over previous
//
#include <hip/hip_runtime.h>

// ---------------------------------------------------------------------------
// DistanceLoss pipeline on MI355X (gfx950)  — R22
//
// R20 (best 213.9us): 3-stage ring, 3 blocks/CU, distance-2 prefetch,
//      counted vmcnt(2), split-K=2, dist_stats merge pass.
// R21 (466us FAIL-perf): last-block finalize w/ device fences — cross-XCD
//      fence serialization (Guideline 16). REVERTED.
// R22: NO SPLIT-K (the fence-free way to kill partial traffic):
//      - gemm1 grid(8,32)=256 blocks (1/CU, balanced), K=2048, single Y
//        (build_e2 reads 16.8MB not 33.6MB, no adds)
//      - gemm2 grid(36,9)=324 blocks, K=2048, epilogue computes
//        D = sqrt(sq_r+sq_c-2*acc) straight from registers: no partial
//        writes/re-reads, no dist_stats pass, no atomics, no fences
//      - stats_only (read-only) replaces dist_stats
//      - tail_fused @512 thr (R21c, arithmetic-identical)
//
//  1. prep: W fp32->split bf16; X bf16; zero record/sq
//  2. gemm_ring grid(8,32):  Y = X @ Wsplit^T  (fp32)
//  3. build_e2: E rows (bf16) from Y, sample-tiled; sq via atomics
//  4. gemm_ring grid(36,9):  D = sqrt(sq_r+sq_c-2 E@Esup^T)  (fused epilogue)
//  5. stats_only(3375): per-(c,i) ave/pos/rmax from D rows
//  6. record_part(675)
//  7. tail_fused(75x512): thr/mask/msum + masked row sums + logits
// ---------------------------------------------------------------------------

typedef __bf16 bf16x8 __attribute__((ext_vector_type(8)));
typedef float f32x4 __attribute__((ext_vector_type(4)));

#define NQT   3375      // 75*45 query-tuple rows
#define MROWS 4500      // 3375 query rows + 1125 support rows
#define MPAD  4608      // 36 * 128
#define LDD   1152      // padded 1125 -> 9*128
#define BK    32        // K-tile; LDS stride = 32 (UNPADDED: required by global_load_lds)

__constant__ int P0[45] = {0,0,0,0,0,0,0,0,0,
                           1,1,1,1,1,1,1,1,
                           2,2,2,2,2,2,2,
                           3,3,3,3,3,3,
                           4,4,4,4,4,
                           5,5,5,5,
                           6,6,6,
                           7,7,
                           8};
__constant__ int P1[45] = {1,2,3,4,5,6,7,8,9,
                           2,3,4,5,6,7,8,9,
                           3,4,5,6,7,8,9,
                           4,5,6,7,8,9,
                           5,6,7,8,9,
                           6,7,8,9,
                           7,8,9,
                           8,9,
                           9};

__device__ inline unsigned short f2b(float x) {
  __bf16 b = (__bf16)x;               // RNE
  return __builtin_bit_cast(unsigned short, b);
}
__device__ inline float b2f(unsigned int u16) {
  return __uint_as_float(u16 << 16);
}

// async global->LDS, 16B per lane; lds dest must be wave-uniform base + lane*16
__device__ __forceinline__ void gl_lds16(const unsigned short* g, unsigned short* l) {
  __builtin_amdgcn_global_load_lds(
      (__attribute__((address_space(1))) void*)(g),
      (__attribute__((address_space(3))) void*)(l),
      16, 0, 0);
}

// ---- 1: prep: conv W (split) + conv X + zero record/sq ---------------------
__global__ void prep(const float* __restrict__ W, const float* __restrict__ Q,
                     const float* __restrict__ Sp,
                     unsigned short* __restrict__ Ws, unsigned short* __restrict__ X,
                     float* __restrict__ record, float* __restrict__ sq) {
  int b = blockIdx.x, tid = threadIdx.x;
  if (b < 8192) {                                    // W -> split bf16
    int i = b * 256 + tid;
    int i4 = i << 2;
    int o  = i4 >> 12;
    int k  = i4 & 4095;
    int hf = k >> 11;
    int kk = k & 2047;
    float4 v = reinterpret_cast<const float4*>(W)[i];
    ushort4 u;
    u.x = f2b(v.x); u.y = f2b(v.y); u.z = f2b(v.z); u.w = f2b(v.w);
    *reinterpret_cast<ushort4*>(Ws + (size_t)(o + hf * 2048) * 2048 + kk) = u;
  } else if (b < 10240) {                            // X = bf16(Q || S), pad 0
    int i = (b - 8192) * 256 + tid;
    ushort4 u = {0, 0, 0, 0};
    if (i < 384000) {                                // 750*2048/4
      float4 v = reinterpret_cast<const float4*>(Q)[i];
      u.x = f2b(v.x); u.y = f2b(v.y); u.z = f2b(v.z); u.w = f2b(v.w);
    } else if (i < 512000) {                         // + 250*2048/4
      float4 v = reinterpret_cast<const float4*>(Sp)[i - 384000];
      u.x = f2b(v.x); u.y = f2b(v.y); u.z = f2b(v.z); u.w = f2b(v.w);
    }
    reinterpret_cast<ushort4*>(X)[i] = u;
  } else {                                           // zero record + sq
    int i = (b - 10240) * 256 + tid;
    if (i < 4500) record[i] = 0.f;
    else if (i < 9108) sq[i - 4500] = 0.f;
  }
}

// ---- 2/4: bf16 MFMA GEMM, C = A @ B^T, 128x128 tile, BK=32, NO split-K -----
// 512 threads / 8 waves (2x4 wave grid, 64x32 output per wave).
// 3-stage ring (48 KB -> 3 blocks/CU), distance-2 prefetch, counted vmcnt(2).
// If sqv != nullptr: fused distance epilogue writes
//   Pout[r][c] = sqrt(max(sqv[r] + sqv[NQT+c] - 2*acc, 0))  (no partials).
__global__ __launch_bounds__(512)
void gemm_ring(const unsigned short* __restrict__ A, const unsigned short* __restrict__ B,
               int lda, int ldb, int K,
               float* __restrict__ Pout, int ldd,
               const float* __restrict__ sqv) {
  __shared__ unsigned short As[3][128 * BK];   // 3 x 8 KB
  __shared__ unsigned short Bs[3][128 * BK];
  const int tid  = threadIdx.x;
  const int wave = tid >> 6, lane = tid & 63;
  const int quad = lane >> 4, l16 = lane & 15;
  const int wm = (wave >> 2) * 64, wn = (wave & 3) * 32;
  const int m0 = blockIdx.x * 128, n0 = blockIdx.y * 128;

  f32x4 acc[4][2];
#pragma unroll
  for (int i = 0; i < 4; ++i)
#pragma unroll
    for (int j = 0; j < 2; ++j) {
      f32x4 z = {0.f, 0.f, 0.f, 0.f};
      acc[i][j] = z;
    }

  const int r0  = tid >> 2;                          // 0..127
  const int qsw = (tid & 3) ^ ((tid >> 3) & 3);      // swizzled global chunk
  const int kp0 = qsw * 8;
  const int rsw = (quad ^ ((l16 >> 1) & 3)) * 8;     // conflict-free read slot
  const unsigned short* pa = A + (size_t)(m0 + r0) * lda + kp0;
  const unsigned short* pb = B + (size_t)(n0 + r0) * ldb + kp0;
  const int NKi = K / BK;                            // 64

// one full 128-row stage per array: 512 threads x 16B = 8 KB
#define ISSUE(kk, st) do {                                 \
    gl_lds16(pa + (size_t)(kk) * BK, &As[st][wave * 512]); \
    gl_lds16(pb + (size_t)(kk) * BK, &Bs[st][wave * 512]); \
  } while (0)

  ISSUE(0, 0);
  ISSUE(1, 1);
  asm volatile("s_waitcnt vmcnt(2)" ::: "memory");   // tile 0 resident; 1 in flight
  __builtin_amdgcn_s_barrier();

  int sc = 0;
  for (int k = 0; k < NKi; ++k) {
    int sn = sc + 2; if (sn >= 3) sn -= 3;
    if (k + 2 < NKi) ISSUE(k + 2, sn);               // distance-2 prefetch
    bf16x8 af[4], bfr[2];
#pragma unroll
    for (int t = 0; t < 4; ++t)
      af[t] = *reinterpret_cast<const bf16x8*>(&As[sc][(wm + t * 16 + l16) * BK + rsw]);
#pragma unroll
    for (int t = 0; t < 2; ++t)
      bfr[t] = *reinterpret_cast<const bf16x8*>(&Bs[sc][(wn + t * 16 + l16) * BK + rsw]);
#pragma unroll
    for (int i = 0; i < 4; ++i)
#pragma unroll
      for (int j = 0; j < 2; ++j)
        acc[i][j] = __builtin_amdgcn_mfma_f32_16x16x32_bf16(af[i], bfr[j], acc[i][j], 0, 0, 0);
    if (k + 1 < NKi) {
      // guarantee tile k+1 resident; leave k+2 (if issued) in flight
      if (k + 2 < NKi) asm volatile("s_waitcnt vmcnt(2)" ::: "memory");
      else             asm volatile("s_waitcnt vmcnt(0)" ::: "memory");
      __builtin_amdgcn_s_barrier();
    }
    sc = sc + 1; if (sc >= 3) sc = 0;
  }
#undef ISSUE
  asm volatile("s_waitcnt vmcnt(0)" ::: "memory");   // drain before stores

  // epilogue: C/D layout col=lane&15, row=quad*4+reg
  if (sqv == nullptr) {
#pragma unroll
    for (int i = 0; i < 4; ++i)
#pragma unroll
      for (int j = 0; j < 2; ++j) {
        int col = n0 + wn + j * 16 + l16;
        int rbase = m0 + wm + i * 16 + quad * 4;
        f32x4 v = acc[i][j];
#pragma unroll
        for (int r = 0; r < 4; ++r)
          Pout[(size_t)(rbase + r) * ldd + col] = v[r];
      }
  } else {
    // fused distance: D = sqrt(max(sq_r + sq_c - 2*acc, 0))
#pragma unroll
    for (int i = 0; i < 4; ++i) {
      int rbase = m0 + wm + i * 16 + quad * 4;
      float sr[4];
#pragma unroll
      for (int r = 0; r < 4; ++r) sr[r] = sqv[rbase + r];
#pragma unroll
      for (int j = 0; j < 2; ++j) {
        int col = n0 + wn + j * 16 + l16;
        float scq = sqv[NQT + col];
        f32x4 v = acc[i][j];
#pragma unroll
        for (int r = 0; r < 4; ++r)
          Pout[(size_t)(rbase + r) * ldd + col] =
              sqrtf(fmaxf(sr[r] + scq - 2.f * v[r], 0.f));
      }
    }
  }
}

// ---- 3: build_e2: sample-tiled E construction (single Y input) -------------
__global__ __launch_bounds__(256)
void build_e2(const float* __restrict__ Y, const float* __restrict__ bias,
              unsigned short* __restrict__ E, float* __restrict__ sq) {
  int b = blockIdx.x, tid = threadIdx.x;
  if (b >= 400) {                       // zero pad rows
    const size_t base = (size_t)4500 * 2048 / 8;   // uint4 index
    const int total = 108 * 2048 / 8;              // 27648
    uint4 z = {0, 0, 0, 0};
    for (int i = (b - 400) * 256 + tid; i < total; i += 512)
      reinterpret_cast<uint4*>(E)[base + i] = z;
    return;
  }
  int n = b >> 2, q = b & 3;
  int c0 = q * 512;
  __shared__ float Lf[10][512];
  __shared__ float Rf[10][512];
  // stage: 10 frames x 512 cols x {left,right}
  for (int e = tid; e < 1280; e += 256) {           // 1280 float4 slots per array
    int f  = e >> 7;                                // 128 float4 per frame
    int cc = (e & 127) << 2;
    const float* ya = Y + (size_t)(n * 10 + f) * 4096;
    float4 L = *reinterpret_cast<const float4*>(ya + c0 + cc);
    float4 R = *reinterpret_cast<const float4*>(ya + 2048 + c0 + cc);
    *reinterpret_cast<float4*>(&Lf[f][cc]) = L;
    *reinterpret_cast<float4*>(&Rf[f][cc]) = R;
  }
  __syncthreads();
  int wv = tid >> 6, lane = tid & 63;
  int erow0 = (n < 75) ? n * 45 : NQT + (n - 75) * 45;
  for (int t = wv; t < 45; t += 4) {
    int f0 = P0[t], f1 = P1[t];
    int row = erow0 + t;
    float s = 0.f;
#pragma unroll
    for (int k = 0; k < 8; ++k) {
      int c = lane + 64 * k;                        // 0..511
      float x = Lf[f0][c] + Rf[f1][c] + bias[c0 + c];
      x = fmaxf(x, 0.f);
      unsigned short ob = f2b(x);
      E[(size_t)row * 2048 + c0 + c] = ob;
      float xr = b2f(ob);
      s += xr * xr;                                 // norm from rounded value
    }
#pragma unroll
    for (int sh = 32; sh > 0; sh >>= 1) s += __shfl_down(s, sh, 64);
    if (lane == 0) atomicAdd(&sq[row], s);
  }
}

// ---- 5: stats_only: per-class stats for query rows (D already final) -------
__global__ __launch_bounds__(320)
void stats_only(const float* __restrict__ D, float* __restrict__ ave,
                int* __restrict__ pos, float* __restrict__ rmax) {
  __shared__ float drow[LDD];
  __shared__ float sm[5][64];
  int row = blockIdx.x, tid = threadIdx.x;          // row 0..3374
  if (tid < 288) {                                  // 288 float4 = 1152 cols
    size_t ix = (size_t)row * LDD / 4 + tid;
    reinterpret_cast<float4*>(drow)[tid] = reinterpret_cast<const float4*>(D)[ix];
  }
  __syncthreads();
  int wv = tid >> 6, lane = tid & 63;               // wv = class 0..4
  const float* p = &drow[wv * 225];
  float best = -1e30f; int bi = 225;
  float gm = -1e30f;
  if (lane < 60) {
#pragma unroll
    for (int r = 0; r < 4; ++r) {
      int j = lane + 60 * r;
      if (j < 225) {
        float v = p[j];
        if (v > best) { best = v; bi = j; }          // first-occurrence (j asc)
        gm = fmaxf(gm, v);
      }
    }
  }
#pragma unroll
  for (int s = 32; s > 0; s >>= 1) {
    float vv = __shfl_down(best, s, 64);
    int   ii = __shfl_down(bi,   s, 64);
    if (vv > best || (vv == best && ii < bi)) { best = vv; bi = ii; }
  }
  sm[wv][lane] = gm;
  __builtin_amdgcn_wave_barrier();
  if (lane < 5) {
    float m = -1e30f;
#pragma unroll
    for (int a = 0; a < 12; ++a) m = fmaxf(m, sm[wv][lane + 5 * a]);
    sm[wv][lane] = m;
  }
  __builtin_amdgcn_wave_barrier();
  if (lane == 0) {
    float s5 = sm[wv][0] + sm[wv][1] + sm[wv][2] + sm[wv][3] + sm[wv][4];
    ave[wv * NQT + row]  = s5 * 0.2f;
    pos[wv * NQT + row]  = bi;
    rmax[wv * NQT + row] = best;
  }
}

// ---- 6a: record counts, 675 blocks (5 classes x 135 chunks of 25) ----------
__global__ void record_part(const float* __restrict__ D, const float* __restrict__ ave,
                            const int* __restrict__ pos, float* __restrict__ record) {
  int b = blockIdx.x;
  int c = b / 135, chunk = b - c * 135;
  int i0 = chunk * 25;
  int tid = threadIdx.x;
  __shared__ int   sp[25];
  __shared__ float sa[25];
  if (tid < 25) {
    sp[tid] = pos[c * NQT + i0 + tid];
    sa[tid] = ave[c * NQT + i0 + tid];
  }
  __syncthreads();
  float cnt[4] = {0.f, 0.f, 0.f, 0.f};
  int gcol[4];
#pragma unroll
  for (int j = 0; j < 4; ++j) {
    int col = tid + j * 256;
    gcol[j] = (col < 900) ? (col < c * 225 ? col : col + 225) : 0;
  }
  const bool act3 = (tid + 768) < 900;
  const float* Dsup = D + (size_t)(NQT + c * 225) * LDD;
  for (int ii = 0; ii < 25; ++ii) {
    const float* row = Dsup + (size_t)sp[ii] * LDD;
    float a = sa[ii];
    cnt[0] += (row[gcol[0]] > a) ? 1.f : 0.f;
    cnt[1] += (row[gcol[1]] > a) ? 1.f : 0.f;
    cnt[2] += (row[gcol[2]] > a) ? 1.f : 0.f;
    if (act3) cnt[3] += (row[gcol[3]] > a) ? 1.f : 0.f;
  }
#pragma unroll
  for (int j = 0; j < 4; ++j) {
    int col = tid + j * 256;
    if (col < 900) atomicAdd(&record[c * 900 + col], cnt[j]);
  }
}

// ---- 7: tail_fused: thr/mask/msum + masked row sums + logits ---------------
// 75 blocks x 512 threads (8 waves). Masks recomputed per-block from record
// (integer-valued floats -> sums exact -> identical thr/mask/msum).
__global__ __launch_bounds__(512)
void tail_fused(const float* __restrict__ D, const float* __restrict__ record,
                const float* __restrict__ rmax, float* __restrict__ out) {
  int q = blockIdx.x;                                // 0..74
  int tid = threadIdx.x;
  int wv = tid >> 6, lane = tid & 63;
  __shared__ float maskT[5 * LDD];                   // 23 KB
  __shared__ float msum_s[5];
  __shared__ float St[5][45];
  for (int i = tid; i < 5 * LDD; i += 512) maskT[i] = 0.f;
  if (tid < 5) msum_s[tid] = 0.f;
  __syncthreads();

  // Phase A: 20 segments (c,mi), one wave each, strided over 8 waves
  for (int seg = wv; seg < 20; seg += 8) {
    int c = seg >> 2, mi = seg & 3;
    const float* rec = record + c * 900 + mi * 225;
    float r0 = rec[lane];
    float r1 = rec[lane + 64];
    float r2 = rec[lane + 128];
    float r3 = (lane + 192 < 225) ? rec[lane + 192] : 0.f;
    float s  = r0 + r1 + r2 + r3;
    float nz = (r0 != 0.f ? 1.f : 0.f) + (r1 != 0.f ? 1.f : 0.f) +
               (r2 != 0.f ? 1.f : 0.f) + (r3 != 0.f ? 1.f : 0.f);
#pragma unroll
    for (int sh = 32; sh > 0; sh >>= 1) {
      s  += __shfl_down(s,  sh, 64);
      nz += __shfl_down(nz, sh, 64);
    }
    s  = __shfl(s,  0, 64);
    nz = __shfl(nz, 0, 64);
    float nzc = nz < 1.f ? 1.f : nz;
    float thr = s / nzc;
    float mcount = 0.f;
    float rv[4] = {r0, r1, r2, r3};
#pragma unroll
    for (int j = 0; j < 4; ++j) {
      int idx = lane + j * 64;
      if (idx < 225) {
        float m = (rv[j] < thr) ? 1.f : 0.f;
        int L = mi * 225 + idx;                      // local col 0..899
        int g = L + (L >= c * 225 ? 225 : 0);        // global support col
        maskT[c * LDD + g] = m;
        mcount += m;
      }
    }
#pragma unroll
    for (int sh = 32; sh > 0; sh >>= 1) mcount += __shfl_down(mcount, sh, 64);
    if (lane == 0) atomicAdd(&msum_s[c], mcount);
  }
  __syncthreads();

  // Phase B: rows t = wv, wv+8, ... (45 rows over 8 waves)
  for (int t = wv; t < 45; t += 8) {
    const float* row = D + (size_t)(q * 45 + t) * LDD;
    float a0 = 0.f, a1 = 0.f, a2 = 0.f, a3 = 0.f, a4 = 0.f;
#pragma unroll
    for (int k = 0; k < 18; ++k) {                   // 18*64 = 1152 cols
      int col = k * 64 + lane;
      float d = row[col];
      a0 += d * maskT[0 * LDD + col];
      a1 += d * maskT[1 * LDD + col];
      a2 += d * maskT[2 * LDD + col];
      a3 += d * maskT[3 * LDD + col];
      a4 += d * maskT[4 * LDD + col];
    }
#pragma unroll
    for (int sh = 32; sh > 0; sh >>= 1) {
      a0 += __shfl_down(a0, sh, 64);
      a1 += __shfl_down(a1, sh, 64);
      a2 += __shfl_down(a2, sh, 64);
      a3 += __shfl_down(a3, sh, 64);
      a4 += __shfl_down(a4, sh, 64);
    }
    if (lane == 0) {
      St[0][t] = a0; St[1][t] = a1; St[2][t] = a2; St[3][t] = a3; St[4][t] = a4;
    }
  }
  __syncthreads();

  // Phase C: per-class aggregate + logits
  if (tid < 5) {
    int c = tid;
    float dsum = 0.f, ssum = 0.f;
    for (int t = 0; t < 45; ++t) {
      dsum += rmax[c * NQT + q * 45 + t];
      ssum += St[c][t];
    }
    float dm = dsum / 45.f;
    float ms = msum_s[c]; if (ms < 1.f) ms = 1.f;
    float contrast = ssum / (ms * 180.f);            // /msum /45 /(WAY-1)
    out[q * 5 + c] = dm;
    out[375 + q * 5 + c] = dm / (contrast + dm);
  }
}

// ---------------------------------------------------------------------------
extern "C" void kernel_launch(void* const* d_in, const int* in_sizes, int n_in,
                              void* d_out, int out_size, void* d_ws, size_t ws_size,
                              hipStream_t stream) {
  const float* support = (const float*)d_in[0];
  // d_in[1] = support_labels (arange//SHOT) -- class gather is a reshape, unused
  const float* queries = (const float*)d_in[2];
  const float* W       = (const float*)d_in[3];
  const float* bias    = (const float*)d_in[4];
  float* out = (float*)d_out;

  // Workspace layout (lifetimes):
  //  [0, 21.2 MB):   Xb (4.2) + Ws (16.8)  -- dead after gemm1
  //  [21.2, 38.0):   Y (fp32 1024x4096)    -- dead after build_e2
  //  [38.0, 59.2):   D (fp32 4608x1152)
  //  [59.2, 78.1):   Eb (bf16 4608x2048)
  //  then smalls
  char* ws = (char*)d_ws;
  size_t off = 0;
  unsigned short* Xb  = (unsigned short*)(ws + off);
  unsigned short* Wsp = (unsigned short*)(ws + off + 4194304);
  off += 21233664;
  float*          Y   = (float*)(ws + off);          off += (size_t)1024 * 4096 * 4;
  float*          Dm  = (float*)(ws + off);          off += (size_t)MPAD * LDD * 4;
  unsigned short* Eb  = (unsigned short*)(ws + off); off += (size_t)MPAD * 2048 * 2;
  float* sq      = (float*)(ws + off); off += 4608 * 4 + 256;
  float* ave     = (float*)(ws + off); off += 5 * NQT * 4 + 256;
  int*   pos     = (int*)(ws + off);   off += 5 * NQT * 4 + 256;
  float* rmax    = (float*)(ws + off); off += 5 * NQT * 4 + 256;
  float* record  = (float*)(ws + off); off += 5 * 900 * 4 + 256;

  // zero tail: 4500 (record) + 4608 (sq) = 9108 -> 36 blocks
  prep<<<10276, 256, 0, stream>>>(W, queries, support, Wsp, Xb, record, sq);

  dim3 g1(1024 / 128, 4096 / 128);      // 8 x 32 = 256 blocks, K=2048
  gemm_ring<<<g1, 512, 0, stream>>>(Xb, Wsp, 2048, 2048, 2048, Y, 4096, nullptr);

  build_e2<<<402, 256, 0, stream>>>(Y, bias, Eb, sq);

  dim3 g2(MPAD / 128, LDD / 128);       // 36 x 9 = 324 blocks, K=2048
  gemm_ring<<<g2, 512, 0, stream>>>(Eb, Eb + (size_t)NQT * 2048, 2048, 2048, 2048,
                                    Dm, LDD, sq);

  stats_only<<<NQT, 320, 0, stream>>>(Dm, ave, pos, rmax);

  record_part<<<675, 256, 0, stream>>>(Dm, ave, pos, record);
  tail_fused<<<75, 512, 0, stream>>>(Dm, record, rmax, out);
}

// Round 9
// 204.874 us; speedup vs baseline: 2.2746x; 1.1051x over previous
//
#include <hip/hip_runtime.h>

// ---------------------------------------------------------------------------
// DistanceLoss pipeline on MI355X (gfx950)  — R23
//
// R20 (verified best, 213.9us): split-K=2 GEMMs, 3-stage ring (48KB ->
//      3 blocks/CU), distance-2 prefetch, counted vmcnt(2), dist_stats
//      merge pass, record_part, tail_fused@512.
// R21 (466us): last-block finalize w/ device fences — cross-XCD fence
//      serialization. REVERTED.
// R22 (226us): no-split-K — gemm2 tail imbalance (+6.5us) and gemm1
//      1-block/CU occupancy loss (+~10us) beat the saved merge pass.
//      REVERTED.
// R23 = R20 + ONE variable: Y-partials stored as BF16 (template
//      gemm_ring<BF16OUT>). Y only feeds relu->bf16 E, so fp32 partial
//      precision is wasted; cuts 34MB off the gemm1->build_e2 hop.
//      gemm2 partial path (fp32) byte-identical to R20.
//
//  1. prep: W fp32->split bf16; X bf16; zero record/sq
//  2. gemm_ring<true> grid(8,32,2):  Yz = X @ Wsplit^T (bf16 half-K partials)
//  3. build_e2: E rows (bf16) from Y0+Y1 (bf16 reads), sq via atomics
//  4. gemm_ring<false> grid(36,9,2): Pz = E @ Esup^T (fp32 half-K partials)
//  5. dist_stats: D = sqrt(...), + per-(c,i) stats for query rows
//  6. record_part(675)
//  7. tail_fused(75x512): thr/mask/msum + masked row sums + logits
// ---------------------------------------------------------------------------

typedef __bf16 bf16x8 __attribute__((ext_vector_type(8)));
typedef float f32x4 __attribute__((ext_vector_type(4)));

#define NQT   3375      // 75*45 query-tuple rows
#define MROWS 4500      // 3375 query rows + 1125 support rows
#define MPAD  4608      // 36 * 128
#define LDD   1152      // padded 1125 -> 9*128
#define BK    32        // K-tile; LDS stride = 32 (UNPADDED: required by global_load_lds)

__constant__ int P0[45] = {0,0,0,0,0,0,0,0,0,
                           1,1,1,1,1,1,1,1,
                           2,2,2,2,2,2,2,
                           3,3,3,3,3,3,
                           4,4,4,4,4,
                           5,5,5,5,
                           6,6,6,
                           7,7,
                           8};
__constant__ int P1[45] = {1,2,3,4,5,6,7,8,9,
                           2,3,4,5,6,7,8,9,
                           3,4,5,6,7,8,9,
                           4,5,6,7,8,9,
                           5,6,7,8,9,
                           6,7,8,9,
                           7,8,9,
                           8,9,
                           9};

__device__ inline unsigned short f2b(float x) {
  __bf16 b = (__bf16)x;               // RNE
  return __builtin_bit_cast(unsigned short, b);
}
__device__ inline float b2f(unsigned int u16) {
  return __uint_as_float(u16 << 16);
}

// async global->LDS, 16B per lane; lds dest must be wave-uniform base + lane*16
__device__ __forceinline__ void gl_lds16(const unsigned short* g, unsigned short* l) {
  __builtin_amdgcn_global_load_lds(
      (__attribute__((address_space(1))) void*)(g),
      (__attribute__((address_space(3))) void*)(l),
      16, 0, 0);
}

// ---- 1: prep: conv W (split) + conv X + zero record/sq ---------------------
__global__ void prep(const float* __restrict__ W, const float* __restrict__ Q,
                     const float* __restrict__ Sp,
                     unsigned short* __restrict__ Ws, unsigned short* __restrict__ X,
                     float* __restrict__ record, float* __restrict__ sq) {
  int b = blockIdx.x, tid = threadIdx.x;
  if (b < 8192) {                                    // W -> split bf16
    int i = b * 256 + tid;
    int i4 = i << 2;
    int o  = i4 >> 12;
    int k  = i4 & 4095;
    int hf = k >> 11;
    int kk = k & 2047;
    float4 v = reinterpret_cast<const float4*>(W)[i];
    ushort4 u;
    u.x = f2b(v.x); u.y = f2b(v.y); u.z = f2b(v.z); u.w = f2b(v.w);
    *reinterpret_cast<ushort4*>(Ws + (size_t)(o + hf * 2048) * 2048 + kk) = u;
  } else if (b < 10240) {                            // X = bf16(Q || S), pad 0
    int i = (b - 8192) * 256 + tid;
    ushort4 u = {0, 0, 0, 0};
    if (i < 384000) {                                // 750*2048/4
      float4 v = reinterpret_cast<const float4*>(Q)[i];
      u.x = f2b(v.x); u.y = f2b(v.y); u.z = f2b(v.z); u.w = f2b(v.w);
    } else if (i < 512000) {                         // + 250*2048/4
      float4 v = reinterpret_cast<const float4*>(Sp)[i - 384000];
      u.x = f2b(v.x); u.y = f2b(v.y); u.z = f2b(v.z); u.w = f2b(v.w);
    }
    reinterpret_cast<ushort4*>(X)[i] = u;
  } else {                                           // zero record + sq
    int i = (b - 10240) * 256 + tid;
    if (i < 4500) record[i] = 0.f;
    else if (i < 9108) sq[i - 4500] = 0.f;
  }
}

// ---- 2/4: bf16 MFMA GEMM, C = A @ B^T, 128x128 tile, BK=32, split-K --------
// 512 threads / 8 waves (2x4 wave grid, 64x32 output per wave).
// 3-stage ring (48 KB -> 3 blocks/CU), distance-2 prefetch, counted vmcnt(2)
// (tile k+1 resident, k+2 in flight across the barrier).
// BF16OUT: partials stored as bf16 (gemm1 path; Y only feeds relu->bf16 E).
template <bool BF16OUT>
__global__ __launch_bounds__(512)
void gemm_ring(const unsigned short* __restrict__ A, const unsigned short* __restrict__ B,
               int lda, int ldb, int Ksplit,
               float* __restrict__ Pout0, float* __restrict__ Pout1, int ldd) {
  __shared__ unsigned short As[3][128 * BK];   // 3 x 8 KB
  __shared__ unsigned short Bs[3][128 * BK];
  const int tid  = threadIdx.x;
  const int wave = tid >> 6, lane = tid & 63;
  const int quad = lane >> 4, l16 = lane & 15;
  const int wm = (wave >> 2) * 64, wn = (wave & 3) * 32;
  const int m0 = blockIdx.x * 128, n0 = blockIdx.y * 128;
  const int kbase = blockIdx.z * Ksplit;

  f32x4 acc[4][2];
#pragma unroll
  for (int i = 0; i < 4; ++i)
#pragma unroll
    for (int j = 0; j < 2; ++j) {
      f32x4 z = {0.f, 0.f, 0.f, 0.f};
      acc[i][j] = z;
    }

  const int r0  = tid >> 2;                          // 0..127
  const int qsw = (tid & 3) ^ ((tid >> 3) & 3);      // swizzled global chunk
  const int kp0 = qsw * 8;
  const int rsw = (quad ^ ((l16 >> 1) & 3)) * 8;     // conflict-free read slot
  const unsigned short* pa = A + (size_t)(m0 + r0) * lda + kbase + kp0;
  const unsigned short* pb = B + (size_t)(n0 + r0) * ldb + kbase + kp0;
  const int NKi = Ksplit / BK;                       // 32

// one full 128-row stage per array: 512 threads x 16B = 8 KB
#define ISSUE(kk, st) do {                                 \
    gl_lds16(pa + (size_t)(kk) * BK, &As[st][wave * 512]); \
    gl_lds16(pb + (size_t)(kk) * BK, &Bs[st][wave * 512]); \
  } while (0)

  ISSUE(0, 0);
  ISSUE(1, 1);
  asm volatile("s_waitcnt vmcnt(2)" ::: "memory");   // tile 0 resident; 1 in flight
  __builtin_amdgcn_s_barrier();

  int sc = 0;
  for (int k = 0; k < NKi; ++k) {
    int sn = sc + 2; if (sn >= 3) sn -= 3;
    if (k + 2 < NKi) ISSUE(k + 2, sn);               // distance-2 prefetch
    bf16x8 af[4], bfr[2];
#pragma unroll
    for (int t = 0; t < 4; ++t)
      af[t] = *reinterpret_cast<const bf16x8*>(&As[sc][(wm + t * 16 + l16) * BK + rsw]);
#pragma unroll
    for (int t = 0; t < 2; ++t)
      bfr[t] = *reinterpret_cast<const bf16x8*>(&Bs[sc][(wn + t * 16 + l16) * BK + rsw]);
#pragma unroll
    for (int i = 0; i < 4; ++i)
#pragma unroll
      for (int j = 0; j < 2; ++j)
        acc[i][j] = __builtin_amdgcn_mfma_f32_16x16x32_bf16(af[i], bfr[j], acc[i][j], 0, 0, 0);
    if (k + 1 < NKi) {
      // guarantee tile k+1 resident; leave k+2 (if issued) in flight
      if (k + 2 < NKi) asm volatile("s_waitcnt vmcnt(2)" ::: "memory");
      else             asm volatile("s_waitcnt vmcnt(0)" ::: "memory");
      __builtin_amdgcn_s_barrier();
    }
    sc = sc + 1; if (sc >= 3) sc = 0;
  }
#undef ISSUE
  asm volatile("s_waitcnt vmcnt(0)" ::: "memory");   // drain before stores

  float* Pout = blockIdx.z ? Pout1 : Pout0;
  // epilogue: C/D layout col=lane&15, row=quad*4+reg
  if (BF16OUT) {
    unsigned short* PoutU = reinterpret_cast<unsigned short*>(Pout);
#pragma unroll
    for (int i = 0; i < 4; ++i)
#pragma unroll
      for (int j = 0; j < 2; ++j) {
        int col = n0 + wn + j * 16 + l16;
        int rbase = m0 + wm + i * 16 + quad * 4;
        f32x4 v = acc[i][j];
#pragma unroll
        for (int r = 0; r < 4; ++r)
          PoutU[(size_t)(rbase + r) * ldd + col] = f2b(v[r]);
      }
  } else {
#pragma unroll
    for (int i = 0; i < 4; ++i)
#pragma unroll
      for (int j = 0; j < 2; ++j) {
        int col = n0 + wn + j * 16 + l16;
        int rbase = m0 + wm + i * 16 + quad * 4;
        f32x4 v = acc[i][j];
#pragma unroll
        for (int r = 0; r < 4; ++r)
          Pout[(size_t)(rbase + r) * ldd + col] = v[r];
      }
  }
}

// ---- 3: build_e2: sample-tiled E construction (bf16 Y partials) ------------
__global__ __launch_bounds__(256)
void build_e2(const unsigned short* __restrict__ Y0, const unsigned short* __restrict__ Y1,
              const float* __restrict__ bias,
              unsigned short* __restrict__ E, float* __restrict__ sq) {
  int b = blockIdx.x, tid = threadIdx.x;
  if (b >= 400) {                       // zero pad rows
    const size_t base = (size_t)4500 * 2048 / 8;   // uint4 index
    const int total = 108 * 2048 / 8;              // 27648
    uint4 z = {0, 0, 0, 0};
    for (int i = (b - 400) * 256 + tid; i < total; i += 512)
      reinterpret_cast<uint4*>(E)[base + i] = z;
    return;
  }
  int n = b >> 2, q = b & 3;
  int c0 = q * 512;
  __shared__ float Lf[10][512];
  __shared__ float Rf[10][512];
  // stage: 10 frames x 512 cols x {left,right}, Y0+Y1 summed (bf16 reads)
  for (int e = tid; e < 1280; e += 256) {           // 1280 4-col slots per array
    int f  = e >> 7;                                // 128 slots per frame
    int cc = (e & 127) << 2;
    const unsigned short* ya = Y0 + (size_t)(n * 10 + f) * 4096;
    const unsigned short* yb = Y1 + (size_t)(n * 10 + f) * 4096;
    ushort4 l0 = *reinterpret_cast<const ushort4*>(ya + c0 + cc);
    ushort4 l1 = *reinterpret_cast<const ushort4*>(yb + c0 + cc);
    ushort4 r0 = *reinterpret_cast<const ushort4*>(ya + 2048 + c0 + cc);
    ushort4 r1 = *reinterpret_cast<const ushort4*>(yb + 2048 + c0 + cc);
    float4 L = {b2f(l0.x) + b2f(l1.x), b2f(l0.y) + b2f(l1.y),
                b2f(l0.z) + b2f(l1.z), b2f(l0.w) + b2f(l1.w)};
    float4 R = {b2f(r0.x) + b2f(r1.x), b2f(r0.y) + b2f(r1.y),
                b2f(r0.z) + b2f(r1.z), b2f(r0.w) + b2f(r1.w)};
    *reinterpret_cast<float4*>(&Lf[f][cc]) = L;
    *reinterpret_cast<float4*>(&Rf[f][cc]) = R;
  }
  __syncthreads();
  int wv = tid >> 6, lane = tid & 63;
  int erow0 = (n < 75) ? n * 45 : NQT + (n - 75) * 45;
  for (int t = wv; t < 45; t += 4) {
    int f0 = P0[t], f1 = P1[t];
    int row = erow0 + t;
    float s = 0.f;
#pragma unroll
    for (int k = 0; k < 8; ++k) {
      int c = lane + 64 * k;                        // 0..511
      float x = Lf[f0][c] + Rf[f1][c] + bias[c0 + c];
      x = fmaxf(x, 0.f);
      unsigned short ob = f2b(x);
      E[(size_t)row * 2048 + c0 + c] = ob;
      float xr = b2f(ob);
      s += xr * xr;                                 // norm from rounded value
    }
#pragma unroll
    for (int sh = 32; sh > 0; sh >>= 1) s += __shfl_down(s, sh, 64);
    if (lane == 0) atomicAdd(&sq[row], s);
  }
}

// ---- 5: dist_stats: D from partials + per-class stats (fused) --------------
__global__ __launch_bounds__(320)
void dist_stats(const float* __restrict__ Pa, const float* __restrict__ Pb,
                const float* __restrict__ sq, float* __restrict__ D,
                float* __restrict__ ave, int* __restrict__ pos,
                float* __restrict__ rmax) {
  __shared__ float drow[LDD];
  __shared__ float sm[5][64];
  int row = blockIdx.x, tid = threadIdx.x;
  float sr = sq[row];
  if (tid < 288) {                                   // 288 float4 = 1152 cols
    int c = tid * 4;
    size_t ix = (size_t)row * LDD / 4 + tid;
    float4 a = reinterpret_cast<const float4*>(Pa)[ix];
    float4 bb = reinterpret_cast<const float4*>(Pb)[ix];
    float4 o;
    o.x = sqrtf(fmaxf(sr + sq[NQT + c + 0] - 2.f * (a.x + bb.x), 0.f));
    o.y = sqrtf(fmaxf(sr + sq[NQT + c + 1] - 2.f * (a.y + bb.y), 0.f));
    o.z = sqrtf(fmaxf(sr + sq[NQT + c + 2] - 2.f * (a.z + bb.z), 0.f));
    o.w = sqrtf(fmaxf(sr + sq[NQT + c + 3] - 2.f * (a.w + bb.w), 0.f));
    reinterpret_cast<float4*>(D)[ix] = o;
    *reinterpret_cast<float4*>(&drow[c]) = o;
  }
  __syncthreads();
  if (row >= NQT) return;                            // support rows: D only
  int wv = tid >> 6, lane = tid & 63;                // wv = class 0..4
  const float* p = &drow[wv * 225];
  float best = -1e30f; int bi = 225;
  float gm = -1e30f;
  if (lane < 60) {
#pragma unroll
    for (int r = 0; r < 4; ++r) {
      int j = lane + 60 * r;
      if (j < 225) {
        float v = p[j];
        if (v > best) { best = v; bi = j; }          // first-occurrence (j asc)
        gm = fmaxf(gm, v);
      }
    }
  }
#pragma unroll
  for (int s = 32; s > 0; s >>= 1) {
    float vv = __shfl_down(best, s, 64);
    int   ii = __shfl_down(bi,   s, 64);
    if (vv > best || (vv == best && ii < bi)) { best = vv; bi = ii; }
  }
  sm[wv][lane] = gm;
  __builtin_amdgcn_wave_barrier();
  if (lane < 5) {
    float m = -1e30f;
#pragma unroll
    for (int a = 0; a < 12; ++a) m = fmaxf(m, sm[wv][lane + 5 * a]);
    sm[wv][lane] = m;
  }
  __builtin_amdgcn_wave_barrier();
  if (lane == 0) {
    float s5 = sm[wv][0] + sm[wv][1] + sm[wv][2] + sm[wv][3] + sm[wv][4];
    ave[wv * NQT + row]  = s5 * 0.2f;
    pos[wv * NQT + row]  = bi;
    rmax[wv * NQT + row] = best;
  }
}

// ---- 6a: record counts, 675 blocks (5 classes x 135 chunks of 25) ----------
__global__ void record_part(const float* __restrict__ D, const float* __restrict__ ave,
                            const int* __restrict__ pos, float* __restrict__ record) {
  int b = blockIdx.x;
  int c = b / 135, chunk = b - c * 135;
  int i0 = chunk * 25;
  int tid = threadIdx.x;
  __shared__ int   sp[25];
  __shared__ float sa[25];
  if (tid < 25) {
    sp[tid] = pos[c * NQT + i0 + tid];
    sa[tid] = ave[c * NQT + i0 + tid];
  }
  __syncthreads();
  float cnt[4] = {0.f, 0.f, 0.f, 0.f};
  int gcol[4];
#pragma unroll
  for (int j = 0; j < 4; ++j) {
    int col = tid + j * 256;
    gcol[j] = (col < 900) ? (col < c * 225 ? col : col + 225) : 0;
  }
  const bool act3 = (tid + 768) < 900;
  const float* Dsup = D + (size_t)(NQT + c * 225) * LDD;
  for (int ii = 0; ii < 25; ++ii) {
    const float* row = Dsup + (size_t)sp[ii] * LDD;
    float a = sa[ii];
    cnt[0] += (row[gcol[0]] > a) ? 1.f : 0.f;
    cnt[1] += (row[gcol[1]] > a) ? 1.f : 0.f;
    cnt[2] += (row[gcol[2]] > a) ? 1.f : 0.f;
    if (act3) cnt[3] += (row[gcol[3]] > a) ? 1.f : 0.f;
  }
#pragma unroll
  for (int j = 0; j < 4; ++j) {
    int col = tid + j * 256;
    if (col < 900) atomicAdd(&record[c * 900 + col], cnt[j]);
  }
}

// ---- 7: tail_fused: thr/mask/msum + masked row sums + logits ---------------
// 75 blocks x 512 threads (8 waves). Masks recomputed per-block from record
// (integer-valued floats -> sums exact -> identical thr/mask/msum).
__global__ __launch_bounds__(512)
void tail_fused(const float* __restrict__ D, const float* __restrict__ record,
                const float* __restrict__ rmax, float* __restrict__ out) {
  int q = blockIdx.x;                                // 0..74
  int tid = threadIdx.x;
  int wv = tid >> 6, lane = tid & 63;
  __shared__ float maskT[5 * LDD];                   // 23 KB
  __shared__ float msum_s[5];
  __shared__ float St[5][45];
  for (int i = tid; i < 5 * LDD; i += 512) maskT[i] = 0.f;
  if (tid < 5) msum_s[tid] = 0.f;
  __syncthreads();

  // Phase A: 20 segments (c,mi), one wave each, strided over 8 waves
  for (int seg = wv; seg < 20; seg += 8) {
    int c = seg >> 2, mi = seg & 3;
    const float* rec = record + c * 900 + mi * 225;
    float r0 = rec[lane];
    float r1 = rec[lane + 64];
    float r2 = rec[lane + 128];
    float r3 = (lane + 192 < 225) ? rec[lane + 192] : 0.f;
    float s  = r0 + r1 + r2 + r3;
    float nz = (r0 != 0.f ? 1.f : 0.f) + (r1 != 0.f ? 1.f : 0.f) +
               (r2 != 0.f ? 1.f : 0.f) + (r3 != 0.f ? 1.f : 0.f);
#pragma unroll
    for (int sh = 32; sh > 0; sh >>= 1) {
      s  += __shfl_down(s,  sh, 64);
      nz += __shfl_down(nz, sh, 64);
    }
    s  = __shfl(s,  0, 64);
    nz = __shfl(nz, 0, 64);
    float nzc = nz < 1.f ? 1.f : nz;
    float thr = s / nzc;
    float mcount = 0.f;
    float rv[4] = {r0, r1, r2, r3};
#pragma unroll
    for (int j = 0; j < 4; ++j) {
      int idx = lane + j * 64;
      if (idx < 225) {
        float m = (rv[j] < thr) ? 1.f : 0.f;
        int L = mi * 225 + idx;                      // local col 0..899
        int g = L + (L >= c * 225 ? 225 : 0);        // global support col
        maskT[c * LDD + g] = m;
        mcount += m;
      }
    }
#pragma unroll
    for (int sh = 32; sh > 0; sh >>= 1) mcount += __shfl_down(mcount, sh, 64);
    if (lane == 0) atomicAdd(&msum_s[c], mcount);
  }
  __syncthreads();

  // Phase B: rows t = wv, wv+8, ... (45 rows over 8 waves)
  for (int t = wv; t < 45; t += 8) {
    const float* row = D + (size_t)(q * 45 + t) * LDD;
    float a0 = 0.f, a1 = 0.f, a2 = 0.f, a3 = 0.f, a4 = 0.f;
#pragma unroll
    for (int k = 0; k < 18; ++k) {                   // 18*64 = 1152 cols
      int col = k * 64 + lane;
      float d = row[col];
      a0 += d * maskT[0 * LDD + col];
      a1 += d * maskT[1 * LDD + col];
      a2 += d * maskT[2 * LDD + col];
      a3 += d * maskT[3 * LDD + col];
      a4 += d * maskT[4 * LDD + col];
    }
#pragma unroll
    for (int sh = 32; sh > 0; sh >>= 1) {
      a0 += __shfl_down(a0, sh, 64);
      a1 += __shfl_down(a1, sh, 64);
      a2 += __shfl_down(a2, sh, 64);
      a3 += __shfl_down(a3, sh, 64);
      a4 += __shfl_down(a4, sh, 64);
    }
    if (lane == 0) {
      St[0][t] = a0; St[1][t] = a1; St[2][t] = a2; St[3][t] = a3; St[4][t] = a4;
    }
  }
  __syncthreads();

  // Phase C: per-class aggregate + logits
  if (tid < 5) {
    int c = tid;
    float dsum = 0.f, ssum = 0.f;
    for (int t = 0; t < 45; ++t) {
      dsum += rmax[c * NQT + q * 45 + t];
      ssum += St[c][t];
    }
    float dm = dsum / 45.f;
    float ms = msum_s[c]; if (ms < 1.f) ms = 1.f;
    float contrast = ssum / (ms * 180.f);            // /msum /45 /(WAY-1)
    out[q * 5 + c] = dm;
    out[375 + q * 5 + c] = dm / (contrast + dm);
  }
}

// ---------------------------------------------------------------------------
extern "C" void kernel_launch(void* const* d_in, const int* in_sizes, int n_in,
                              void* d_out, int out_size, void* d_ws, size_t ws_size,
                              hipStream_t stream) {
  const float* support = (const float*)d_in[0];
  // d_in[1] = support_labels (arange//SHOT) -- class gather is a reshape, unused
  const float* queries = (const float*)d_in[2];
  const float* W       = (const float*)d_in[3];
  const float* bias    = (const float*)d_in[4];
  float* out = (float*)d_out;

  // Aliased workspace layout (lifetimes):
  //  [0, 21.2 MB):  Xb (4.2) + Ws (16.8)   -- dead after gemm1 --> reused as Pd1
  //  [21.2, 38.0):  Y0b + Y1b (bf16, 8.4 MB each) -- dead after build_e2
  //  [38.0, 59.2):  Dm region: Pd0 -> final D
  //  [59.2, 78.1):  Eb (bf16 4608x2048)
  //  then smalls
  char* ws = (char*)d_ws;
  size_t off = 0;
  unsigned short* Xb  = (unsigned short*)(ws + off);
  unsigned short* Wsp = (unsigned short*)(ws + off + 4194304);
  float*          Pd1 = (float*)(ws + off);          off += 21233664;
  unsigned short* Y0b = (unsigned short*)(ws + off); off += (size_t)1024 * 4096 * 2;
  unsigned short* Y1b = (unsigned short*)(ws + off); off += (size_t)1024 * 4096 * 2;
  float*          Dm  = (float*)(ws + off);          off += (size_t)MPAD * LDD * 4;
  unsigned short* Eb  = (unsigned short*)(ws + off); off += (size_t)MPAD * 2048 * 2;
  float* sq      = (float*)(ws + off); off += 4608 * 4 + 256;
  float* ave     = (float*)(ws + off); off += 5 * NQT * 4 + 256;
  int*   pos     = (int*)(ws + off);   off += 5 * NQT * 4 + 256;
  float* rmax    = (float*)(ws + off); off += 5 * NQT * 4 + 256;
  float* record  = (float*)(ws + off); off += 5 * 900 * 4 + 256;

  // zero tail: 4500 (record) + 4608 (sq) = 9108 -> 36 blocks
  prep<<<10276, 256, 0, stream>>>(W, queries, support, Wsp, Xb, record, sq);

  dim3 g1(1024 / 128, 4096 / 128, 2);   // 8 x 32 x 2 = 512 blocks, K=1024 each
  gemm_ring<true><<<g1, 512, 0, stream>>>(Xb, Wsp, 2048, 2048, 1024,
                                          (float*)Y0b, (float*)Y1b, 4096);

  build_e2<<<402, 256, 0, stream>>>(Y0b, Y1b, bias, Eb, sq);

  dim3 g2(MPAD / 128, LDD / 128, 2);    // 36 x 9 x 2 = 648 blocks, K=1024 each
  gemm_ring<false><<<g2, 512, 0, stream>>>(Eb, Eb + (size_t)NQT * 2048, 2048, 2048, 1024,
                                           Dm, Pd1, LDD);

  dist_stats<<<MROWS, 320, 0, stream>>>(Dm, Pd1, sq, Dm, ave, pos, rmax);

  record_part<<<675, 256, 0, stream>>>(Dm, ave, pos, record);
  tail_fused<<<75, 512, 0, stream>>>(Dm, record, rmax, out);
}

// Round 10
// 202.345 us; speedup vs baseline: 2.3030x; 1.0125x over previous
//
#include <hip/hip_runtime.h>

// ---------------------------------------------------------------------------
// DistanceLoss pipeline on MI355X (gfx950)  — R24
//
// R20 (213.9us): split-K=2, 3-stage ring (48KB -> 3 blocks/CU), distance-2
//      prefetch, counted vmcnt(2). R21 (fences) / R22 (no-split-K) reverted.
// R23 (204.9us): Y-partials bf16 — 50MB traffic cut paid -9us; calibrates
//      traffic model at ~1.6us / 10MB.
// R24 = R23 + gemm2 partials ALSO bf16 (same BF16OUT path): 41.5MB fp32
//      partial write+re-read -> 20.7MB each. D noise ~0.05 (0.3%) vs 0.46
//      threshold. Partials alias the dead Xb+Ws region; D fp32 keeps its
//      own region (no read/write overlap in dist_stats).
//
//  1. prep: W fp32->split bf16; X bf16; zero record/sq
//  2. gemm_ring<true> grid(8,32,2):  Yz = X @ Wsplit^T (bf16 half-K partials)
//  3. build_e2: E rows (bf16) from Y0+Y1 (bf16 reads), sq via atomics
//  4. gemm_ring<true> grid(36,9,2):  Pz = E @ Esup^T (bf16 half-K partials)
//  5. dist_stats: D = sqrt(sq_r+sq_c-2(p0+p1)) + per-(c,i) stats
//  6. record_part(675)
//  7. tail_fused(75x512): thr/mask/msum + masked row sums + logits
// ---------------------------------------------------------------------------

typedef __bf16 bf16x8 __attribute__((ext_vector_type(8)));
typedef float f32x4 __attribute__((ext_vector_type(4)));

#define NQT   3375      // 75*45 query-tuple rows
#define MROWS 4500      // 3375 query rows + 1125 support rows
#define MPAD  4608      // 36 * 128
#define LDD   1152      // padded 1125 -> 9*128
#define BK    32        // K-tile; LDS stride = 32 (UNPADDED: required by global_load_lds)

__constant__ int P0[45] = {0,0,0,0,0,0,0,0,0,
                           1,1,1,1,1,1,1,1,
                           2,2,2,2,2,2,2,
                           3,3,3,3,3,3,
                           4,4,4,4,4,
                           5,5,5,5,
                           6,6,6,
                           7,7,
                           8};
__constant__ int P1[45] = {1,2,3,4,5,6,7,8,9,
                           2,3,4,5,6,7,8,9,
                           3,4,5,6,7,8,9,
                           4,5,6,7,8,9,
                           5,6,7,8,9,
                           6,7,8,9,
                           7,8,9,
                           8,9,
                           9};

__device__ inline unsigned short f2b(float x) {
  __bf16 b = (__bf16)x;               // RNE
  return __builtin_bit_cast(unsigned short, b);
}
__device__ inline float b2f(unsigned int u16) {
  return __uint_as_float(u16 << 16);
}

// async global->LDS, 16B per lane; lds dest must be wave-uniform base + lane*16
__device__ __forceinline__ void gl_lds16(const unsigned short* g, unsigned short* l) {
  __builtin_amdgcn_global_load_lds(
      (__attribute__((address_space(1))) void*)(g),
      (__attribute__((address_space(3))) void*)(l),
      16, 0, 0);
}

// ---- 1: prep: conv W (split) + conv X + zero record/sq ---------------------
__global__ void prep(const float* __restrict__ W, const float* __restrict__ Q,
                     const float* __restrict__ Sp,
                     unsigned short* __restrict__ Ws, unsigned short* __restrict__ X,
                     float* __restrict__ record, float* __restrict__ sq) {
  int b = blockIdx.x, tid = threadIdx.x;
  if (b < 8192) {                                    // W -> split bf16
    int i = b * 256 + tid;
    int i4 = i << 2;
    int o  = i4 >> 12;
    int k  = i4 & 4095;
    int hf = k >> 11;
    int kk = k & 2047;
    float4 v = reinterpret_cast<const float4*>(W)[i];
    ushort4 u;
    u.x = f2b(v.x); u.y = f2b(v.y); u.z = f2b(v.z); u.w = f2b(v.w);
    *reinterpret_cast<ushort4*>(Ws + (size_t)(o + hf * 2048) * 2048 + kk) = u;
  } else if (b < 10240) {                            // X = bf16(Q || S), pad 0
    int i = (b - 8192) * 256 + tid;
    ushort4 u = {0, 0, 0, 0};
    if (i < 384000) {                                // 750*2048/4
      float4 v = reinterpret_cast<const float4*>(Q)[i];
      u.x = f2b(v.x); u.y = f2b(v.y); u.z = f2b(v.z); u.w = f2b(v.w);
    } else if (i < 512000) {                         // + 250*2048/4
      float4 v = reinterpret_cast<const float4*>(Sp)[i - 384000];
      u.x = f2b(v.x); u.y = f2b(v.y); u.z = f2b(v.z); u.w = f2b(v.w);
    }
    reinterpret_cast<ushort4*>(X)[i] = u;
  } else {                                           // zero record + sq
    int i = (b - 10240) * 256 + tid;
    if (i < 4500) record[i] = 0.f;
    else if (i < 9108) sq[i - 4500] = 0.f;
  }
}

// ---- 2/4: bf16 MFMA GEMM, C = A @ B^T, 128x128 tile, BK=32, split-K --------
// 512 threads / 8 waves (2x4 wave grid, 64x32 output per wave).
// 3-stage ring (48 KB -> 3 blocks/CU), distance-2 prefetch, counted vmcnt(2)
// (tile k+1 resident, k+2 in flight across the barrier).
// BF16OUT: partials stored as bf16 (both GEMMs in R24).
template <bool BF16OUT>
__global__ __launch_bounds__(512)
void gemm_ring(const unsigned short* __restrict__ A, const unsigned short* __restrict__ B,
               int lda, int ldb, int Ksplit,
               float* __restrict__ Pout0, float* __restrict__ Pout1, int ldd) {
  __shared__ unsigned short As[3][128 * BK];   // 3 x 8 KB
  __shared__ unsigned short Bs[3][128 * BK];
  const int tid  = threadIdx.x;
  const int wave = tid >> 6, lane = tid & 63;
  const int quad = lane >> 4, l16 = lane & 15;
  const int wm = (wave >> 2) * 64, wn = (wave & 3) * 32;
  const int m0 = blockIdx.x * 128, n0 = blockIdx.y * 128;
  const int kbase = blockIdx.z * Ksplit;

  f32x4 acc[4][2];
#pragma unroll
  for (int i = 0; i < 4; ++i)
#pragma unroll
    for (int j = 0; j < 2; ++j) {
      f32x4 z = {0.f, 0.f, 0.f, 0.f};
      acc[i][j] = z;
    }

  const int r0  = tid >> 2;                          // 0..127
  const int qsw = (tid & 3) ^ ((tid >> 3) & 3);      // swizzled global chunk
  const int kp0 = qsw * 8;
  const int rsw = (quad ^ ((l16 >> 1) & 3)) * 8;     // conflict-free read slot
  const unsigned short* pa = A + (size_t)(m0 + r0) * lda + kbase + kp0;
  const unsigned short* pb = B + (size_t)(n0 + r0) * ldb + kbase + kp0;
  const int NKi = Ksplit / BK;                       // 32

// one full 128-row stage per array: 512 threads x 16B = 8 KB
#define ISSUE(kk, st) do {                                 \
    gl_lds16(pa + (size_t)(kk) * BK, &As[st][wave * 512]); \
    gl_lds16(pb + (size_t)(kk) * BK, &Bs[st][wave * 512]); \
  } while (0)

  ISSUE(0, 0);
  ISSUE(1, 1);
  asm volatile("s_waitcnt vmcnt(2)" ::: "memory");   // tile 0 resident; 1 in flight
  __builtin_amdgcn_s_barrier();

  int sc = 0;
  for (int k = 0; k < NKi; ++k) {
    int sn = sc + 2; if (sn >= 3) sn -= 3;
    if (k + 2 < NKi) ISSUE(k + 2, sn);               // distance-2 prefetch
    bf16x8 af[4], bfr[2];
#pragma unroll
    for (int t = 0; t < 4; ++t)
      af[t] = *reinterpret_cast<const bf16x8*>(&As[sc][(wm + t * 16 + l16) * BK + rsw]);
#pragma unroll
    for (int t = 0; t < 2; ++t)
      bfr[t] = *reinterpret_cast<const bf16x8*>(&Bs[sc][(wn + t * 16 + l16) * BK + rsw]);
#pragma unroll
    for (int i = 0; i < 4; ++i)
#pragma unroll
      for (int j = 0; j < 2; ++j)
        acc[i][j] = __builtin_amdgcn_mfma_f32_16x16x32_bf16(af[i], bfr[j], acc[i][j], 0, 0, 0);
    if (k + 1 < NKi) {
      // guarantee tile k+1 resident; leave k+2 (if issued) in flight
      if (k + 2 < NKi) asm volatile("s_waitcnt vmcnt(2)" ::: "memory");
      else             asm volatile("s_waitcnt vmcnt(0)" ::: "memory");
      __builtin_amdgcn_s_barrier();
    }
    sc = sc + 1; if (sc >= 3) sc = 0;
  }
#undef ISSUE
  asm volatile("s_waitcnt vmcnt(0)" ::: "memory");   // drain before stores

  float* Pout = blockIdx.z ? Pout1 : Pout0;
  // epilogue: C/D layout col=lane&15, row=quad*4+reg
  if (BF16OUT) {
    unsigned short* PoutU = reinterpret_cast<unsigned short*>(Pout);
#pragma unroll
    for (int i = 0; i < 4; ++i)
#pragma unroll
      for (int j = 0; j < 2; ++j) {
        int col = n0 + wn + j * 16 + l16;
        int rbase = m0 + wm + i * 16 + quad * 4;
        f32x4 v = acc[i][j];
#pragma unroll
        for (int r = 0; r < 4; ++r)
          PoutU[(size_t)(rbase + r) * ldd + col] = f2b(v[r]);
      }
  } else {
#pragma unroll
    for (int i = 0; i < 4; ++i)
#pragma unroll
      for (int j = 0; j < 2; ++j) {
        int col = n0 + wn + j * 16 + l16;
        int rbase = m0 + wm + i * 16 + quad * 4;
        f32x4 v = acc[i][j];
#pragma unroll
        for (int r = 0; r < 4; ++r)
          Pout[(size_t)(rbase + r) * ldd + col] = v[r];
      }
  }
}

// ---- 3: build_e2: sample-tiled E construction (bf16 Y partials) ------------
__global__ __launch_bounds__(256)
void build_e2(const unsigned short* __restrict__ Y0, const unsigned short* __restrict__ Y1,
              const float* __restrict__ bias,
              unsigned short* __restrict__ E, float* __restrict__ sq) {
  int b = blockIdx.x, tid = threadIdx.x;
  if (b >= 400) {                       // zero pad rows
    const size_t base = (size_t)4500 * 2048 / 8;   // uint4 index
    const int total = 108 * 2048 / 8;              // 27648
    uint4 z = {0, 0, 0, 0};
    for (int i = (b - 400) * 256 + tid; i < total; i += 512)
      reinterpret_cast<uint4*>(E)[base + i] = z;
    return;
  }
  int n = b >> 2, q = b & 3;
  int c0 = q * 512;
  __shared__ float Lf[10][512];
  __shared__ float Rf[10][512];
  // stage: 10 frames x 512 cols x {left,right}, Y0+Y1 summed (bf16 reads)
  for (int e = tid; e < 1280; e += 256) {           // 1280 4-col slots per array
    int f  = e >> 7;                                // 128 slots per frame
    int cc = (e & 127) << 2;
    const unsigned short* ya = Y0 + (size_t)(n * 10 + f) * 4096;
    const unsigned short* yb = Y1 + (size_t)(n * 10 + f) * 4096;
    ushort4 l0 = *reinterpret_cast<const ushort4*>(ya + c0 + cc);
    ushort4 l1 = *reinterpret_cast<const ushort4*>(yb + c0 + cc);
    ushort4 r0 = *reinterpret_cast<const ushort4*>(ya + 2048 + c0 + cc);
    ushort4 r1 = *reinterpret_cast<const ushort4*>(yb + 2048 + c0 + cc);
    float4 L = {b2f(l0.x) + b2f(l1.x), b2f(l0.y) + b2f(l1.y),
                b2f(l0.z) + b2f(l1.z), b2f(l0.w) + b2f(l1.w)};
    float4 R = {b2f(r0.x) + b2f(r1.x), b2f(r0.y) + b2f(r1.y),
                b2f(r0.z) + b2f(r1.z), b2f(r0.w) + b2f(r1.w)};
    *reinterpret_cast<float4*>(&Lf[f][cc]) = L;
    *reinterpret_cast<float4*>(&Rf[f][cc]) = R;
  }
  __syncthreads();
  int wv = tid >> 6, lane = tid & 63;
  int erow0 = (n < 75) ? n * 45 : NQT + (n - 75) * 45;
  for (int t = wv; t < 45; t += 4) {
    int f0 = P0[t], f1 = P1[t];
    int row = erow0 + t;
    float s = 0.f;
#pragma unroll
    for (int k = 0; k < 8; ++k) {
      int c = lane + 64 * k;                        // 0..511
      float x = Lf[f0][c] + Rf[f1][c] + bias[c0 + c];
      x = fmaxf(x, 0.f);
      unsigned short ob = f2b(x);
      E[(size_t)row * 2048 + c0 + c] = ob;
      float xr = b2f(ob);
      s += xr * xr;                                 // norm from rounded value
    }
#pragma unroll
    for (int sh = 32; sh > 0; sh >>= 1) s += __shfl_down(s, sh, 64);
    if (lane == 0) atomicAdd(&sq[row], s);
  }
}

// ---- 5: dist_stats: D from bf16 partials + per-class stats (fused) ---------
__global__ __launch_bounds__(320)
void dist_stats(const unsigned short* __restrict__ Pa, const unsigned short* __restrict__ Pb,
                const float* __restrict__ sq, float* __restrict__ D,
                float* __restrict__ ave, int* __restrict__ pos,
                float* __restrict__ rmax) {
  __shared__ float drow[LDD];
  __shared__ float sm[5][64];
  int row = blockIdx.x, tid = threadIdx.x;
  float sr = sq[row];
  if (tid < 288) {                                   // 288 x 4 cols = 1152
    int c = tid * 4;
    size_t ixu = (size_t)row * LDD + c;
    ushort4 a = *reinterpret_cast<const ushort4*>(Pa + ixu);
    ushort4 bb = *reinterpret_cast<const ushort4*>(Pb + ixu);
    float4 o;
    o.x = sqrtf(fmaxf(sr + sq[NQT + c + 0] - 2.f * (b2f(a.x) + b2f(bb.x)), 0.f));
    o.y = sqrtf(fmaxf(sr + sq[NQT + c + 1] - 2.f * (b2f(a.y) + b2f(bb.y)), 0.f));
    o.z = sqrtf(fmaxf(sr + sq[NQT + c + 2] - 2.f * (b2f(a.z) + b2f(bb.z)), 0.f));
    o.w = sqrtf(fmaxf(sr + sq[NQT + c + 3] - 2.f * (b2f(a.w) + b2f(bb.w)), 0.f));
    reinterpret_cast<float4*>(D)[(size_t)row * LDD / 4 + tid] = o;
    *reinterpret_cast<float4*>(&drow[c]) = o;
  }
  __syncthreads();
  if (row >= NQT) return;                            // support rows: D only
  int wv = tid >> 6, lane = tid & 63;                // wv = class 0..4
  const float* p = &drow[wv * 225];
  float best = -1e30f; int bi = 225;
  float gm = -1e30f;
  if (lane < 60) {
#pragma unroll
    for (int r = 0; r < 4; ++r) {
      int j = lane + 60 * r;
      if (j < 225) {
        float v = p[j];
        if (v > best) { best = v; bi = j; }          // first-occurrence (j asc)
        gm = fmaxf(gm, v);
      }
    }
  }
#pragma unroll
  for (int s = 32; s > 0; s >>= 1) {
    float vv = __shfl_down(best, s, 64);
    int   ii = __shfl_down(bi,   s, 64);
    if (vv > best || (vv == best && ii < bi)) { best = vv; bi = ii; }
  }
  sm[wv][lane] = gm;
  __builtin_amdgcn_wave_barrier();
  if (lane < 5) {
    float m = -1e30f;
#pragma unroll
    for (int a = 0; a < 12; ++a) m = fmaxf(m, sm[wv][lane + 5 * a]);
    sm[wv][lane] = m;
  }
  __builtin_amdgcn_wave_barrier();
  if (lane == 0) {
    float s5 = sm[wv][0] + sm[wv][1] + sm[wv][2] + sm[wv][3] + sm[wv][4];
    ave[wv * NQT + row]  = s5 * 0.2f;
    pos[wv * NQT + row]  = bi;
    rmax[wv * NQT + row] = best;
  }
}

// ---- 6a: record counts, 675 blocks (5 classes x 135 chunks of 25) ----------
__global__ void record_part(const float* __restrict__ D, const float* __restrict__ ave,
                            const int* __restrict__ pos, float* __restrict__ record) {
  int b = blockIdx.x;
  int c = b / 135, chunk = b - c * 135;
  int i0 = chunk * 25;
  int tid = threadIdx.x;
  __shared__ int   sp[25];
  __shared__ float sa[25];
  if (tid < 25) {
    sp[tid] = pos[c * NQT + i0 + tid];
    sa[tid] = ave[c * NQT + i0 + tid];
  }
  __syncthreads();
  float cnt[4] = {0.f, 0.f, 0.f, 0.f};
  int gcol[4];
#pragma unroll
  for (int j = 0; j < 4; ++j) {
    int col = tid + j * 256;
    gcol[j] = (col < 900) ? (col < c * 225 ? col : col + 225) : 0;
  }
  const bool act3 = (tid + 768) < 900;
  const float* Dsup = D + (size_t)(NQT + c * 225) * LDD;
  for (int ii = 0; ii < 25; ++ii) {
    const float* row = Dsup + (size_t)sp[ii] * LDD;
    float a = sa[ii];
    cnt[0] += (row[gcol[0]] > a) ? 1.f : 0.f;
    cnt[1] += (row[gcol[1]] > a) ? 1.f : 0.f;
    cnt[2] += (row[gcol[2]] > a) ? 1.f : 0.f;
    if (act3) cnt[3] += (row[gcol[3]] > a) ? 1.f : 0.f;
  }
#pragma unroll
  for (int j = 0; j < 4; ++j) {
    int col = tid + j * 256;
    if (col < 900) atomicAdd(&record[c * 900 + col], cnt[j]);
  }
}

// ---- 7: tail_fused: thr/mask/msum + masked row sums + logits ---------------
// 75 blocks x 512 threads (8 waves). Masks recomputed per-block from record
// (integer-valued floats -> sums exact -> identical thr/mask/msum).
__global__ __launch_bounds__(512)
void tail_fused(const float* __restrict__ D, const float* __restrict__ record,
                const float* __restrict__ rmax, float* __restrict__ out) {
  int q = blockIdx.x;                                // 0..74
  int tid = threadIdx.x;
  int wv = tid >> 6, lane = tid & 63;
  __shared__ float maskT[5 * LDD];                   // 23 KB
  __shared__ float msum_s[5];
  __shared__ float St[5][45];
  for (int i = tid; i < 5 * LDD; i += 512) maskT[i] = 0.f;
  if (tid < 5) msum_s[tid] = 0.f;
  __syncthreads();

  // Phase A: 20 segments (c,mi), one wave each, strided over 8 waves
  for (int seg = wv; seg < 20; seg += 8) {
    int c = seg >> 2, mi = seg & 3;
    const float* rec = record + c * 900 + mi * 225;
    float r0 = rec[lane];
    float r1 = rec[lane + 64];
    float r2 = rec[lane + 128];
    float r3 = (lane + 192 < 225) ? rec[lane + 192] : 0.f;
    float s  = r0 + r1 + r2 + r3;
    float nz = (r0 != 0.f ? 1.f : 0.f) + (r1 != 0.f ? 1.f : 0.f) +
               (r2 != 0.f ? 1.f : 0.f) + (r3 != 0.f ? 1.f : 0.f);
#pragma unroll
    for (int sh = 32; sh > 0; sh >>= 1) {
      s  += __shfl_down(s,  sh, 64);
      nz += __shfl_down(nz, sh, 64);
    }
    s  = __shfl(s,  0, 64);
    nz = __shfl(nz, 0, 64);
    float nzc = nz < 1.f ? 1.f : nz;
    float thr = s / nzc;
    float mcount = 0.f;
    float rv[4] = {r0, r1, r2, r3};
#pragma unroll
    for (int j = 0; j < 4; ++j) {
      int idx = lane + j * 64;
      if (idx < 225) {
        float m = (rv[j] < thr) ? 1.f : 0.f;
        int L = mi * 225 + idx;                      // local col 0..899
        int g = L + (L >= c * 225 ? 225 : 0);        // global support col
        maskT[c * LDD + g] = m;
        mcount += m;
      }
    }
#pragma unroll
    for (int sh = 32; sh > 0; sh >>= 1) mcount += __shfl_down(mcount, sh, 64);
    if (lane == 0) atomicAdd(&msum_s[c], mcount);
  }
  __syncthreads();

  // Phase B: rows t = wv, wv+8, ... (45 rows over 8 waves)
  for (int t = wv; t < 45; t += 8) {
    const float* row = D + (size_t)(q * 45 + t) * LDD;
    float a0 = 0.f, a1 = 0.f, a2 = 0.f, a3 = 0.f, a4 = 0.f;
#pragma unroll
    for (int k = 0; k < 18; ++k) {                   // 18*64 = 1152 cols
      int col = k * 64 + lane;
      float d = row[col];
      a0 += d * maskT[0 * LDD + col];
      a1 += d * maskT[1 * LDD + col];
      a2 += d * maskT[2 * LDD + col];
      a3 += d * maskT[3 * LDD + col];
      a4 += d * maskT[4 * LDD + col];
    }
#pragma unroll
    for (int sh = 32; sh > 0; sh >>= 1) {
      a0 += __shfl_down(a0, sh, 64);
      a1 += __shfl_down(a1, sh, 64);
      a2 += __shfl_down(a2, sh, 64);
      a3 += __shfl_down(a3, sh, 64);
      a4 += __shfl_down(a4, sh, 64);
    }
    if (lane == 0) {
      St[0][t] = a0; St[1][t] = a1; St[2][t] = a2; St[3][t] = a3; St[4][t] = a4;
    }
  }
  __syncthreads();

  // Phase C: per-class aggregate + logits
  if (tid < 5) {
    int c = tid;
    float dsum = 0.f, ssum = 0.f;
    for (int t = 0; t < 45; ++t) {
      dsum += rmax[c * NQT + q * 45 + t];
      ssum += St[c][t];
    }
    float dm = dsum / 45.f;
    float ms = msum_s[c]; if (ms < 1.f) ms = 1.f;
    float contrast = ssum / (ms * 180.f);            // /msum /45 /(WAY-1)
    out[q * 5 + c] = dm;
    out[375 + q * 5 + c] = dm / (contrast + dm);
  }
}

// ---------------------------------------------------------------------------
extern "C" void kernel_launch(void* const* d_in, const int* in_sizes, int n_in,
                              void* d_out, int out_size, void* d_ws, size_t ws_size,
                              hipStream_t stream) {
  const float* support = (const float*)d_in[0];
  // d_in[1] = support_labels (arange//SHOT) -- class gather is a reshape, unused
  const float* queries = (const float*)d_in[2];
  const float* W       = (const float*)d_in[3];
  const float* bias    = (const float*)d_in[4];
  float* out = (float*)d_out;

  // Aliased workspace layout (lifetimes):
  //  [0, 21.2 MB):  Xb (4.2) + Ws (16.8)  -- dead after gemm1 -->
  //                 Pd0b + Pd1b (bf16 partials, 10.6 MB each)
  //  [21.2, 38.0):  Y0b + Y1b (bf16, 8.4 MB each) -- dead after build_e2
  //  [38.0, 59.2):  D (fp32 4608x1152)
  //  [59.2, 78.1):  Eb (bf16 4608x2048)
  //  then smalls
  char* ws = (char*)d_ws;
  size_t off = 0;
  unsigned short* Xb  = (unsigned short*)(ws + off);
  unsigned short* Wsp = (unsigned short*)(ws + off + 4194304);
  unsigned short* Pd0b = (unsigned short*)(ws + off);
  unsigned short* Pd1b = (unsigned short*)(ws + off + (size_t)MPAD * LDD * 2);
  off += 21233664;
  unsigned short* Y0b = (unsigned short*)(ws + off); off += (size_t)1024 * 4096 * 2;
  unsigned short* Y1b = (unsigned short*)(ws + off); off += (size_t)1024 * 4096 * 2;
  float*          Dm  = (float*)(ws + off);          off += (size_t)MPAD * LDD * 4;
  unsigned short* Eb  = (unsigned short*)(ws + off); off += (size_t)MPAD * 2048 * 2;
  float* sq      = (float*)(ws + off); off += 4608 * 4 + 256;
  float* ave     = (float*)(ws + off); off += 5 * NQT * 4 + 256;
  int*   pos     = (int*)(ws + off);   off += 5 * NQT * 4 + 256;
  float* rmax    = (float*)(ws + off); off += 5 * NQT * 4 + 256;
  float* record  = (float*)(ws + off); off += 5 * 900 * 4 + 256;

  // zero tail: 4500 (record) + 4608 (sq) = 9108 -> 36 blocks
  prep<<<10276, 256, 0, stream>>>(W, queries, support, Wsp, Xb, record, sq);

  dim3 g1(1024 / 128, 4096 / 128, 2);   // 8 x 32 x 2 = 512 blocks, K=1024 each
  gemm_ring<true><<<g1, 512, 0, stream>>>(Xb, Wsp, 2048, 2048, 1024,
                                          (float*)Y0b, (float*)Y1b, 4096);

  build_e2<<<402, 256, 0, stream>>>(Y0b, Y1b, bias, Eb, sq);

  dim3 g2(MPAD / 128, LDD / 128, 2);    // 36 x 9 x 2 = 648 blocks, K=1024 each
  gemm_ring<true><<<g2, 512, 0, stream>>>(Eb, Eb + (size_t)NQT * 2048, 2048, 2048, 1024,
                                          (float*)Pd0b, (float*)Pd1b, LDD);

  dist_stats<<<MROWS, 320, 0, stream>>>(Pd0b, Pd1b, sq, Dm, ave, pos, rmax);

  record_part<<<675, 256, 0, stream>>>(Dm, ave, pos, record);
  tail_fused<<<75, 512, 0, stream>>>(Dm, record, rmax, out);
}

// Round 11
// 201.787 us; speedup vs baseline: 2.3094x; 1.0028x over previous
//
#include <hip/hip_runtime.h>

// ---------------------------------------------------------------------------
// DistanceLoss pipeline on MI355X (gfx950)  — R25
//
// R20 (213.9us): split-K=2, 3-stage ring (48KB -> 3 blocks/CU), distance-2
//      prefetch, counted vmcnt(2). R21 (fences) / R22 (no-split-K) reverted.
// R23 (204.9us): Y-partials bf16 (-9us). R24 (202.3us): gemm2 partials bf16
//      (-2.5us; re-read leg was L2-absorbed).
// R25: D stored as BF16 (last sizable stream): dist_stats writes 10.4MB not
//      20.7; record_part/tail_fused reads halve. Stats computed from the
//      ROUNDED values (self-consistent with what downstream reads).
//      Error budget: D~16, bf16 0.4% -> +-0.06 on outputs, thr 0.46.
//
//  1. prep: W fp32->split bf16; X bf16; zero record/sq
//  2. gemm_ring<true> grid(8,32,2):  Yz = X @ Wsplit^T (bf16 half-K partials)
//  3. build_e2: E rows (bf16) from Y0+Y1 (bf16 reads), sq via atomics
//  4. gemm_ring<true> grid(36,9,2):  Pz = E @ Esup^T (bf16 half-K partials)
//  5. dist_stats: D(bf16) = sqrt(sq_r+sq_c-2(p0+p1)) + per-(c,i) stats
//  6. record_part(675, bf16 D reads)
//  7. tail_fused(75x512, bf16 D reads)
// ---------------------------------------------------------------------------

typedef __bf16 bf16x8 __attribute__((ext_vector_type(8)));
typedef float f32x4 __attribute__((ext_vector_type(4)));

#define NQT   3375      // 75*45 query-tuple rows
#define MROWS 4500      // 3375 query rows + 1125 support rows
#define MPAD  4608      // 36 * 128
#define LDD   1152      // padded 1125 -> 9*128
#define BK    32        // K-tile; LDS stride = 32 (UNPADDED: required by global_load_lds)

__constant__ int P0[45] = {0,0,0,0,0,0,0,0,0,
                           1,1,1,1,1,1,1,1,
                           2,2,2,2,2,2,2,
                           3,3,3,3,3,3,
                           4,4,4,4,4,
                           5,5,5,5,
                           6,6,6,
                           7,7,
                           8};
__constant__ int P1[45] = {1,2,3,4,5,6,7,8,9,
                           2,3,4,5,6,7,8,9,
                           3,4,5,6,7,8,9,
                           4,5,6,7,8,9,
                           5,6,7,8,9,
                           6,7,8,9,
                           7,8,9,
                           8,9,
                           9};

__device__ inline unsigned short f2b(float x) {
  __bf16 b = (__bf16)x;               // RNE
  return __builtin_bit_cast(unsigned short, b);
}
__device__ inline float b2f(unsigned int u16) {
  return __uint_as_float(u16 << 16);
}

// async global->LDS, 16B per lane; lds dest must be wave-uniform base + lane*16
__device__ __forceinline__ void gl_lds16(const unsigned short* g, unsigned short* l) {
  __builtin_amdgcn_global_load_lds(
      (__attribute__((address_space(1))) void*)(g),
      (__attribute__((address_space(3))) void*)(l),
      16, 0, 0);
}

// ---- 1: prep: conv W (split) + conv X + zero record/sq ---------------------
__global__ void prep(const float* __restrict__ W, const float* __restrict__ Q,
                     const float* __restrict__ Sp,
                     unsigned short* __restrict__ Ws, unsigned short* __restrict__ X,
                     float* __restrict__ record, float* __restrict__ sq) {
  int b = blockIdx.x, tid = threadIdx.x;
  if (b < 8192) {                                    // W -> split bf16
    int i = b * 256 + tid;
    int i4 = i << 2;
    int o  = i4 >> 12;
    int k  = i4 & 4095;
    int hf = k >> 11;
    int kk = k & 2047;
    float4 v = reinterpret_cast<const float4*>(W)[i];
    ushort4 u;
    u.x = f2b(v.x); u.y = f2b(v.y); u.z = f2b(v.z); u.w = f2b(v.w);
    *reinterpret_cast<ushort4*>(Ws + (size_t)(o + hf * 2048) * 2048 + kk) = u;
  } else if (b < 10240) {                            // X = bf16(Q || S), pad 0
    int i = (b - 8192) * 256 + tid;
    ushort4 u = {0, 0, 0, 0};
    if (i < 384000) {                                // 750*2048/4
      float4 v = reinterpret_cast<const float4*>(Q)[i];
      u.x = f2b(v.x); u.y = f2b(v.y); u.z = f2b(v.z); u.w = f2b(v.w);
    } else if (i < 512000) {                         // + 250*2048/4
      float4 v = reinterpret_cast<const float4*>(Sp)[i - 384000];
      u.x = f2b(v.x); u.y = f2b(v.y); u.z = f2b(v.z); u.w = f2b(v.w);
    }
    reinterpret_cast<ushort4*>(X)[i] = u;
  } else {                                           // zero record + sq
    int i = (b - 10240) * 256 + tid;
    if (i < 4500) record[i] = 0.f;
    else if (i < 9108) sq[i - 4500] = 0.f;
  }
}

// ---- 2/4: bf16 MFMA GEMM, C = A @ B^T, 128x128 tile, BK=32, split-K --------
// 512 threads / 8 waves (2x4 wave grid, 64x32 output per wave).
// 3-stage ring (48 KB -> 3 blocks/CU), distance-2 prefetch, counted vmcnt(2)
// (tile k+1 resident, k+2 in flight across the barrier).
// BF16OUT: partials stored as bf16 (both GEMMs).
template <bool BF16OUT>
__global__ __launch_bounds__(512)
void gemm_ring(const unsigned short* __restrict__ A, const unsigned short* __restrict__ B,
               int lda, int ldb, int Ksplit,
               float* __restrict__ Pout0, float* __restrict__ Pout1, int ldd) {
  __shared__ unsigned short As[3][128 * BK];   // 3 x 8 KB
  __shared__ unsigned short Bs[3][128 * BK];
  const int tid  = threadIdx.x;
  const int wave = tid >> 6, lane = tid & 63;
  const int quad = lane >> 4, l16 = lane & 15;
  const int wm = (wave >> 2) * 64, wn = (wave & 3) * 32;
  const int m0 = blockIdx.x * 128, n0 = blockIdx.y * 128;
  const int kbase = blockIdx.z * Ksplit;

  f32x4 acc[4][2];
#pragma unroll
  for (int i = 0; i < 4; ++i)
#pragma unroll
    for (int j = 0; j < 2; ++j) {
      f32x4 z = {0.f, 0.f, 0.f, 0.f};
      acc[i][j] = z;
    }

  const int r0  = tid >> 2;                          // 0..127
  const int qsw = (tid & 3) ^ ((tid >> 3) & 3);      // swizzled global chunk
  const int kp0 = qsw * 8;
  const int rsw = (quad ^ ((l16 >> 1) & 3)) * 8;     // conflict-free read slot
  const unsigned short* pa = A + (size_t)(m0 + r0) * lda + kbase + kp0;
  const unsigned short* pb = B + (size_t)(n0 + r0) * ldb + kbase + kp0;
  const int NKi = Ksplit / BK;                       // 32

// one full 128-row stage per array: 512 threads x 16B = 8 KB
#define ISSUE(kk, st) do {                                 \
    gl_lds16(pa + (size_t)(kk) * BK, &As[st][wave * 512]); \
    gl_lds16(pb + (size_t)(kk) * BK, &Bs[st][wave * 512]); \
  } while (0)

  ISSUE(0, 0);
  ISSUE(1, 1);
  asm volatile("s_waitcnt vmcnt(2)" ::: "memory");   // tile 0 resident; 1 in flight
  __builtin_amdgcn_s_barrier();

  int sc = 0;
  for (int k = 0; k < NKi; ++k) {
    int sn = sc + 2; if (sn >= 3) sn -= 3;
    if (k + 2 < NKi) ISSUE(k + 2, sn);               // distance-2 prefetch
    bf16x8 af[4], bfr[2];
#pragma unroll
    for (int t = 0; t < 4; ++t)
      af[t] = *reinterpret_cast<const bf16x8*>(&As[sc][(wm + t * 16 + l16) * BK + rsw]);
#pragma unroll
    for (int t = 0; t < 2; ++t)
      bfr[t] = *reinterpret_cast<const bf16x8*>(&Bs[sc][(wn + t * 16 + l16) * BK + rsw]);
#pragma unroll
    for (int i = 0; i < 4; ++i)
#pragma unroll
      for (int j = 0; j < 2; ++j)
        acc[i][j] = __builtin_amdgcn_mfma_f32_16x16x32_bf16(af[i], bfr[j], acc[i][j], 0, 0, 0);
    if (k + 1 < NKi) {
      // guarantee tile k+1 resident; leave k+2 (if issued) in flight
      if (k + 2 < NKi) asm volatile("s_waitcnt vmcnt(2)" ::: "memory");
      else             asm volatile("s_waitcnt vmcnt(0)" ::: "memory");
      __builtin_amdgcn_s_barrier();
    }
    sc = sc + 1; if (sc >= 3) sc = 0;
  }
#undef ISSUE
  asm volatile("s_waitcnt vmcnt(0)" ::: "memory");   // drain before stores

  float* Pout = blockIdx.z ? Pout1 : Pout0;
  // epilogue: C/D layout col=lane&15, row=quad*4+reg
  if (BF16OUT) {
    unsigned short* PoutU = reinterpret_cast<unsigned short*>(Pout);
#pragma unroll
    for (int i = 0; i < 4; ++i)
#pragma unroll
      for (int j = 0; j < 2; ++j) {
        int col = n0 + wn + j * 16 + l16;
        int rbase = m0 + wm + i * 16 + quad * 4;
        f32x4 v = acc[i][j];
#pragma unroll
        for (int r = 0; r < 4; ++r)
          PoutU[(size_t)(rbase + r) * ldd + col] = f2b(v[r]);
      }
  } else {
#pragma unroll
    for (int i = 0; i < 4; ++i)
#pragma unroll
      for (int j = 0; j < 2; ++j) {
        int col = n0 + wn + j * 16 + l16;
        int rbase = m0 + wm + i * 16 + quad * 4;
        f32x4 v = acc[i][j];
#pragma unroll
        for (int r = 0; r < 4; ++r)
          Pout[(size_t)(rbase + r) * ldd + col] = v[r];
      }
  }
}

// ---- 3: build_e2: sample-tiled E construction (bf16 Y partials) ------------
__global__ __launch_bounds__(256)
void build_e2(const unsigned short* __restrict__ Y0, const unsigned short* __restrict__ Y1,
              const float* __restrict__ bias,
              unsigned short* __restrict__ E, float* __restrict__ sq) {
  int b = blockIdx.x, tid = threadIdx.x;
  if (b >= 400) {                       // zero pad rows
    const size_t base = (size_t)4500 * 2048 / 8;   // uint4 index
    const int total = 108 * 2048 / 8;              // 27648
    uint4 z = {0, 0, 0, 0};
    for (int i = (b - 400) * 256 + tid; i < total; i += 512)
      reinterpret_cast<uint4*>(E)[base + i] = z;
    return;
  }
  int n = b >> 2, q = b & 3;
  int c0 = q * 512;
  __shared__ float Lf[10][512];
  __shared__ float Rf[10][512];
  // stage: 10 frames x 512 cols x {left,right}, Y0+Y1 summed (bf16 reads)
  for (int e = tid; e < 1280; e += 256) {           // 1280 4-col slots per array
    int f  = e >> 7;                                // 128 slots per frame
    int cc = (e & 127) << 2;
    const unsigned short* ya = Y0 + (size_t)(n * 10 + f) * 4096;
    const unsigned short* yb = Y1 + (size_t)(n * 10 + f) * 4096;
    ushort4 l0 = *reinterpret_cast<const ushort4*>(ya + c0 + cc);
    ushort4 l1 = *reinterpret_cast<const ushort4*>(yb + c0 + cc);
    ushort4 r0 = *reinterpret_cast<const ushort4*>(ya + 2048 + c0 + cc);
    ushort4 r1 = *reinterpret_cast<const ushort4*>(yb + 2048 + c0 + cc);
    float4 L = {b2f(l0.x) + b2f(l1.x), b2f(l0.y) + b2f(l1.y),
                b2f(l0.z) + b2f(l1.z), b2f(l0.w) + b2f(l1.w)};
    float4 R = {b2f(r0.x) + b2f(r1.x), b2f(r0.y) + b2f(r1.y),
                b2f(r0.z) + b2f(r1.z), b2f(r0.w) + b2f(r1.w)};
    *reinterpret_cast<float4*>(&Lf[f][cc]) = L;
    *reinterpret_cast<float4*>(&Rf[f][cc]) = R;
  }
  __syncthreads();
  int wv = tid >> 6, lane = tid & 63;
  int erow0 = (n < 75) ? n * 45 : NQT + (n - 75) * 45;
  for (int t = wv; t < 45; t += 4) {
    int f0 = P0[t], f1 = P1[t];
    int row = erow0 + t;
    float s = 0.f;
#pragma unroll
    for (int k = 0; k < 8; ++k) {
      int c = lane + 64 * k;                        // 0..511
      float x = Lf[f0][c] + Rf[f1][c] + bias[c0 + c];
      x = fmaxf(x, 0.f);
      unsigned short ob = f2b(x);
      E[(size_t)row * 2048 + c0 + c] = ob;
      float xr = b2f(ob);
      s += xr * xr;                                 // norm from rounded value
    }
#pragma unroll
    for (int sh = 32; sh > 0; sh >>= 1) s += __shfl_down(s, sh, 64);
    if (lane == 0) atomicAdd(&sq[row], s);
  }
}

// ---- 5: dist_stats: D(bf16) from bf16 partials + per-class stats -----------
// Stats computed from the ROUNDED bf16 values (self-consistent with what
// record_part/tail_fused read back).
__global__ __launch_bounds__(320)
void dist_stats(const unsigned short* __restrict__ Pa, const unsigned short* __restrict__ Pb,
                const float* __restrict__ sq, unsigned short* __restrict__ D,
                float* __restrict__ ave, int* __restrict__ pos,
                float* __restrict__ rmax) {
  __shared__ float drow[LDD];
  __shared__ float sm[5][64];
  int row = blockIdx.x, tid = threadIdx.x;
  float sr = sq[row];
  if (tid < 288) {                                   // 288 x 4 cols = 1152
    int c = tid * 4;
    size_t ixu = (size_t)row * LDD + c;
    ushort4 a = *reinterpret_cast<const ushort4*>(Pa + ixu);
    ushort4 bb = *reinterpret_cast<const ushort4*>(Pb + ixu);
    ushort4 ob;
    ob.x = f2b(sqrtf(fmaxf(sr + sq[NQT + c + 0] - 2.f * (b2f(a.x) + b2f(bb.x)), 0.f)));
    ob.y = f2b(sqrtf(fmaxf(sr + sq[NQT + c + 1] - 2.f * (b2f(a.y) + b2f(bb.y)), 0.f)));
    ob.z = f2b(sqrtf(fmaxf(sr + sq[NQT + c + 2] - 2.f * (b2f(a.z) + b2f(bb.z)), 0.f)));
    ob.w = f2b(sqrtf(fmaxf(sr + sq[NQT + c + 3] - 2.f * (b2f(a.w) + b2f(bb.w)), 0.f)));
    *reinterpret_cast<ushort4*>(D + ixu) = ob;
    float4 o = {b2f(ob.x), b2f(ob.y), b2f(ob.z), b2f(ob.w)};   // rounded
    *reinterpret_cast<float4*>(&drow[c]) = o;
  }
  __syncthreads();
  if (row >= NQT) return;                            // support rows: D only
  int wv = tid >> 6, lane = tid & 63;                // wv = class 0..4
  const float* p = &drow[wv * 225];
  float best = -1e30f; int bi = 225;
  float gm = -1e30f;
  if (lane < 60) {
#pragma unroll
    for (int r = 0; r < 4; ++r) {
      int j = lane + 60 * r;
      if (j < 225) {
        float v = p[j];
        if (v > best) { best = v; bi = j; }          // first-occurrence (j asc)
        gm = fmaxf(gm, v);
      }
    }
  }
#pragma unroll
  for (int s = 32; s > 0; s >>= 1) {
    float vv = __shfl_down(best, s, 64);
    int   ii = __shfl_down(bi,   s, 64);
    if (vv > best || (vv == best && ii < bi)) { best = vv; bi = ii; }
  }
  sm[wv][lane] = gm;
  __builtin_amdgcn_wave_barrier();
  if (lane < 5) {
    float m = -1e30f;
#pragma unroll
    for (int a = 0; a < 12; ++a) m = fmaxf(m, sm[wv][lane + 5 * a]);
    sm[wv][lane] = m;
  }
  __builtin_amdgcn_wave_barrier();
  if (lane == 0) {
    float s5 = sm[wv][0] + sm[wv][1] + sm[wv][2] + sm[wv][3] + sm[wv][4];
    ave[wv * NQT + row]  = s5 * 0.2f;
    pos[wv * NQT + row]  = bi;
    rmax[wv * NQT + row] = best;
  }
}

// ---- 6a: record counts, 675 blocks (bf16 D reads) --------------------------
__global__ void record_part(const unsigned short* __restrict__ D, const float* __restrict__ ave,
                            const int* __restrict__ pos, float* __restrict__ record) {
  int b = blockIdx.x;
  int c = b / 135, chunk = b - c * 135;
  int i0 = chunk * 25;
  int tid = threadIdx.x;
  __shared__ int   sp[25];
  __shared__ float sa[25];
  if (tid < 25) {
    sp[tid] = pos[c * NQT + i0 + tid];
    sa[tid] = ave[c * NQT + i0 + tid];
  }
  __syncthreads();
  float cnt[4] = {0.f, 0.f, 0.f, 0.f};
  int gcol[4];
#pragma unroll
  for (int j = 0; j < 4; ++j) {
    int col = tid + j * 256;
    gcol[j] = (col < 900) ? (col < c * 225 ? col : col + 225) : 0;
  }
  const bool act3 = (tid + 768) < 900;
  const unsigned short* Dsup = D + (size_t)(NQT + c * 225) * LDD;
  for (int ii = 0; ii < 25; ++ii) {
    const unsigned short* row = Dsup + (size_t)sp[ii] * LDD;
    float a = sa[ii];
    cnt[0] += (b2f(row[gcol[0]]) > a) ? 1.f : 0.f;
    cnt[1] += (b2f(row[gcol[1]]) > a) ? 1.f : 0.f;
    cnt[2] += (b2f(row[gcol[2]]) > a) ? 1.f : 0.f;
    if (act3) cnt[3] += (b2f(row[gcol[3]]) > a) ? 1.f : 0.f;
  }
#pragma unroll
  for (int j = 0; j < 4; ++j) {
    int col = tid + j * 256;
    if (col < 900) atomicAdd(&record[c * 900 + col], cnt[j]);
  }
}

// ---- 7: tail_fused: thr/mask/msum + masked row sums + logits ---------------
// 75 blocks x 512 threads (8 waves); bf16 D reads.
__global__ __launch_bounds__(512)
void tail_fused(const unsigned short* __restrict__ D, const float* __restrict__ record,
                const float* __restrict__ rmax, float* __restrict__ out) {
  int q = blockIdx.x;                                // 0..74
  int tid = threadIdx.x;
  int wv = tid >> 6, lane = tid & 63;
  __shared__ float maskT[5 * LDD];                   // 23 KB
  __shared__ float msum_s[5];
  __shared__ float St[5][45];
  for (int i = tid; i < 5 * LDD; i += 512) maskT[i] = 0.f;
  if (tid < 5) msum_s[tid] = 0.f;
  __syncthreads();

  // Phase A: 20 segments (c,mi), one wave each, strided over 8 waves
  for (int seg = wv; seg < 20; seg += 8) {
    int c = seg >> 2, mi = seg & 3;
    const float* rec = record + c * 900 + mi * 225;
    float r0 = rec[lane];
    float r1 = rec[lane + 64];
    float r2 = rec[lane + 128];
    float r3 = (lane + 192 < 225) ? rec[lane + 192] : 0.f;
    float s  = r0 + r1 + r2 + r3;
    float nz = (r0 != 0.f ? 1.f : 0.f) + (r1 != 0.f ? 1.f : 0.f) +
               (r2 != 0.f ? 1.f : 0.f) + (r3 != 0.f ? 1.f : 0.f);
#pragma unroll
    for (int sh = 32; sh > 0; sh >>= 1) {
      s  += __shfl_down(s,  sh, 64);
      nz += __shfl_down(nz, sh, 64);
    }
    s  = __shfl(s,  0, 64);
    nz = __shfl(nz, 0, 64);
    float nzc = nz < 1.f ? 1.f : nz;
    float thr = s / nzc;
    float mcount = 0.f;
    float rv[4] = {r0, r1, r2, r3};
#pragma unroll
    for (int j = 0; j < 4; ++j) {
      int idx = lane + j * 64;
      if (idx < 225) {
        float m = (rv[j] < thr) ? 1.f : 0.f;
        int L = mi * 225 + idx;                      // local col 0..899
        int g = L + (L >= c * 225 ? 225 : 0);        // global support col
        maskT[c * LDD + g] = m;
        mcount += m;
      }
    }
#pragma unroll
    for (int sh = 32; sh > 0; sh >>= 1) mcount += __shfl_down(mcount, sh, 64);
    if (lane == 0) atomicAdd(&msum_s[c], mcount);
  }
  __syncthreads();

  // Phase B: rows t = wv, wv+8, ... (45 rows over 8 waves)
  for (int t = wv; t < 45; t += 8) {
    const unsigned short* row = D + (size_t)(q * 45 + t) * LDD;
    float a0 = 0.f, a1 = 0.f, a2 = 0.f, a3 = 0.f, a4 = 0.f;
#pragma unroll
    for (int k = 0; k < 18; ++k) {                   // 18*64 = 1152 cols
      int col = k * 64 + lane;
      float d = b2f(row[col]);
      a0 += d * maskT[0 * LDD + col];
      a1 += d * maskT[1 * LDD + col];
      a2 += d * maskT[2 * LDD + col];
      a3 += d * maskT[3 * LDD + col];
      a4 += d * maskT[4 * LDD + col];
    }
#pragma unroll
    for (int sh = 32; sh > 0; sh >>= 1) {
      a0 += __shfl_down(a0, sh, 64);
      a1 += __shfl_down(a1, sh, 64);
      a2 += __shfl_down(a2, sh, 64);
      a3 += __shfl_down(a3, sh, 64);
      a4 += __shfl_down(a4, sh, 64);
    }
    if (lane == 0) {
      St[0][t] = a0; St[1][t] = a1; St[2][t] = a2; St[3][t] = a3; St[4][t] = a4;
    }
  }
  __syncthreads();

  // Phase C: per-class aggregate + logits
  if (tid < 5) {
    int c = tid;
    float dsum = 0.f, ssum = 0.f;
    for (int t = 0; t < 45; ++t) {
      dsum += rmax[c * NQT + q * 45 + t];
      ssum += St[c][t];
    }
    float dm = dsum / 45.f;
    float ms = msum_s[c]; if (ms < 1.f) ms = 1.f;
    float contrast = ssum / (ms * 180.f);            // /msum /45 /(WAY-1)
    out[q * 5 + c] = dm;
    out[375 + q * 5 + c] = dm / (contrast + dm);
  }
}

// ---------------------------------------------------------------------------
extern "C" void kernel_launch(void* const* d_in, const int* in_sizes, int n_in,
                              void* d_out, int out_size, void* d_ws, size_t ws_size,
                              hipStream_t stream) {
  const float* support = (const float*)d_in[0];
  // d_in[1] = support_labels (arange//SHOT) -- class gather is a reshape, unused
  const float* queries = (const float*)d_in[2];
  const float* W       = (const float*)d_in[3];
  const float* bias    = (const float*)d_in[4];
  float* out = (float*)d_out;

  // Aliased workspace layout (lifetimes):
  //  [0, 21.2 MB):  Xb (4.2) + Ws (16.8)  -- dead after gemm1 -->
  //                 Pd0b + Pd1b (bf16 partials, 10.6 MB each)
  //  [21.2, 38.0):  Y0b + Y1b (bf16, 8.4 MB each) -- dead after build_e2
  //  [38.0, 48.7):  D (bf16 4608x1152)
  //  [48.7, 67.5):  Eb (bf16 4608x2048)
  //  then smalls
  char* ws = (char*)d_ws;
  size_t off = 0;
  unsigned short* Xb  = (unsigned short*)(ws + off);
  unsigned short* Wsp = (unsigned short*)(ws + off + 4194304);
  unsigned short* Pd0b = (unsigned short*)(ws + off);
  unsigned short* Pd1b = (unsigned short*)(ws + off + (size_t)MPAD * LDD * 2);
  off += 21233664;
  unsigned short* Y0b = (unsigned short*)(ws + off); off += (size_t)1024 * 4096 * 2;
  unsigned short* Y1b = (unsigned short*)(ws + off); off += (size_t)1024 * 4096 * 2;
  unsigned short* Dm  = (unsigned short*)(ws + off); off += (size_t)MPAD * LDD * 2;
  unsigned short* Eb  = (unsigned short*)(ws + off); off += (size_t)MPAD * 2048 * 2;
  float* sq      = (float*)(ws + off); off += 4608 * 4 + 256;
  float* ave     = (float*)(ws + off); off += 5 * NQT * 4 + 256;
  int*   pos     = (int*)(ws + off);   off += 5 * NQT * 4 + 256;
  float* rmax    = (float*)(ws + off); off += 5 * NQT * 4 + 256;
  float* record  = (float*)(ws + off); off += 5 * 900 * 4 + 256;

  // zero tail: 4500 (record) + 4608 (sq) = 9108 -> 36 blocks
  prep<<<10276, 256, 0, stream>>>(W, queries, support, Wsp, Xb, record, sq);

  dim3 g1(1024 / 128, 4096 / 128, 2);   // 8 x 32 x 2 = 512 blocks, K=1024 each
  gemm_ring<true><<<g1, 512, 0, stream>>>(Xb, Wsp, 2048, 2048, 1024,
                                          (float*)Y0b, (float*)Y1b, 4096);

  build_e2<<<402, 256, 0, stream>>>(Y0b, Y1b, bias, Eb, sq);

  dim3 g2(MPAD / 128, LDD / 128, 2);    // 36 x 9 x 2 = 648 blocks, K=1024 each
  gemm_ring<true><<<g2, 512, 0, stream>>>(Eb, Eb + (size_t)NQT * 2048, 2048, 2048, 1024,
                                          (float*)Pd0b, (float*)Pd1b, LDD);

  dist_stats<<<MROWS, 320, 0, stream>>>(Pd0b, Pd1b, sq, Dm, ave, pos, rmax);

  record_part<<<675, 256, 0, stream>>>(Dm, ave, pos, record);
  tail_fused<<<75, 512, 0, stream>>>(Dm, record, rmax, out);
}